// Round 1
// baseline (921.210 us; speedup 1.0000x reference)
//
#include <hip/hip_runtime.h>

// WTConv2d: 3-level Haar DWT -> 5x5 conv (256ch) per level -> IDWT pyramid + bias.
// Convs as implicit GEMM with bf16 MFMA 16x16x32, padded-NHWC input (no bounds checks),
// global_load_lds(16B) staging with source-side XOR swizzle.

typedef unsigned short u16;
typedef __attribute__((ext_vector_type(8))) __bf16 bf16x8;
typedef __attribute__((ext_vector_type(4))) float f32x4;

__device__ __forceinline__ u16 f2bf(float f) {
  union { float f; unsigned u; } v; v.f = f;
  unsigned r = v.u + 0x7fffu + ((v.u >> 16) & 1u);   // RNE
  return (u16)(r >> 16);
}
__device__ __forceinline__ float bf2f(u16 u) {
  union { unsigned u; float f; } v; v.u = ((unsigned)u) << 16;
  return v.f;
}

typedef const unsigned int __attribute__((address_space(1)))* gas1_t;
typedef unsigned int __attribute__((address_space(3)))* gas3_t;
__device__ __forceinline__ void gload16(const void* g, void* l) {
  __builtin_amdgcn_global_load_lds((gas1_t)g, (gas3_t)l, 16, 0, 0);
}

// ---------------- weight transform: OIHW fp32 -> [tap][co][ci] bf16 ----------------
__global__ void k_wtrans(const float* __restrict__ w, u16* __restrict__ wb) {
  int co = blockIdx.x;           // 256
  int ci = threadIdx.x;          // 256
  const float* src = w + ((long)co * 256 + ci) * 25;
  float v[25];
#pragma unroll
  for (int tp = 0; tp < 25; ++tp) v[tp] = src[tp];
#pragma unroll
  for (int tp = 0; tp < 25; ++tp)
    wb[((long)tp * 256 + co) * 256 + ci] = f2bf(v[tp]);
}

// ---------------- DWT: fp32 NCHW [B,64,2H2,2W2] -> stacked bf16 padded NHWC + ll fp32 ----
// stacked dims [B][H2+4][W2+4][256], channel = 4*c + {ll,lh,hl,hh}; border must be pre-zeroed.
__global__ void k_dwt(const float* __restrict__ in, u16* __restrict__ st,
                      float* __restrict__ ll, int B_, int H2, int W2) {
  int idx = blockIdx.x * blockDim.x + threadIdx.x;
  int W2h = W2 >> 1;
  int total = B_ * 64 * H2 * W2h;
  if (idx >= total) return;
  int w2h = idx % W2h; int t2 = idx / W2h;
  int h2 = t2 % H2; t2 /= H2;
  int c = t2 % 64; int b = t2 / 64;
  int w2 = w2h * 2;
  const float* r0 = in + (((long)(b * 64 + c) * (2 * H2) + 2 * h2) * (2 * W2)) + 2 * w2;
  const float* r1 = r0 + 2 * W2;
  float4 tp = *(const float4*)r0;   // a0 b0 a1 b1
  float4 bt = *(const float4*)r1;   // c0 d0 c1 d1
  float ll0 = 0.5f * (tp.x + tp.y + bt.x + bt.y);
  float lh0 = 0.5f * (tp.x + tp.y - bt.x - bt.y);
  float hl0 = 0.5f * (tp.x - tp.y + bt.x - bt.y);
  float hh0 = 0.5f * (tp.x - tp.y - bt.x + bt.y);
  float ll1 = 0.5f * (tp.z + tp.w + bt.z + bt.w);
  float lh1 = 0.5f * (tp.z + tp.w - bt.z - bt.w);
  float hl1 = 0.5f * (tp.z - tp.w + bt.z - bt.w);
  float hh1 = 0.5f * (tp.z - tp.w - bt.z + bt.w);
  long sbase = (((long)b * (H2 + 4) + (h2 + 2)) * (W2 + 4) + (w2 + 2)) * 256 + 4 * c;
  *(ushort4*)(st + sbase)       = make_ushort4(f2bf(ll0), f2bf(lh0), f2bf(hl0), f2bf(hh0));
  *(ushort4*)(st + sbase + 256) = make_ushort4(f2bf(ll1), f2bf(lh1), f2bf(hl1), f2bf(hh1));
  long lbase = (((long)(b * 64 + c) * H2) + h2) * W2 + w2;
  *(float2*)(ll + lbase) = make_float2(ll0, ll1);
}

// ---------------- conv implicit GEMM ----------------
// st: padded NHWC bf16 [B][H2+4][W2+4][256]; wt: [25][256][256] bf16; y: [B*H2*W2][256] bf16.
// Block: 128(m) x 128(n) tile, 4 waves (2x2), BK=64, K=25 taps * 4 ci-chunks.
__global__ __launch_bounds__(256) void k_conv(
    const u16* __restrict__ st, const u16* __restrict__ wt, u16* __restrict__ y,
    int H2, int W2) {
  __shared__ __align__(16) char smem[32768];   // A: [0,16K), B: [16K,32K)
  const int t = threadIdx.x;
  const int lane = t & 63;
  const int wv = t >> 6;
  const int wm = wv >> 1, wn = wv & 1;
  const int m0 = blockIdx.x * 128;
  const int n0 = blockIdx.y * 128;
  const int PW = W2 + 4;
  const int lsub = lane & 7;           // 16B slot within 128B row
  const int lrow8 = lane >> 3;         // row within 8-row chunk
  const int srcci = (lsub ^ lrow8) * 8; // source-side XOR swizzle (elements)

  const char* baseA[4];
  const char* baseB[4];
#pragma unroll
  for (int l = 0; l < 4; ++l) {
    int ml = (wv * 4 + l) * 8 + lrow8;
    int m = m0 + ml;
    int w = m % W2;
    int q = m / W2;
    int h = q % H2;
    int b = q / H2;
    long sp = ((long)(b * (H2 + 4) + h + 2) * PW + (w + 2));
    baseA[l] = (const char*)(st + sp * 256 + srcci);
    int nl = n0 + (wv * 4 + l) * 8 + lrow8;
    baseB[l] = (const char*)(wt + (long)nl * 256 + srcci);
  }

  f32x4 acc[4][4];
#pragma unroll
  for (int i = 0; i < 4; ++i)
#pragma unroll
    for (int j = 0; j < 4; ++j) acc[i][j] = f32x4{0.f, 0.f, 0.f, 0.f};

  // LDS fragment read offsets (swizzled to match staging)
  const int arow = wm * 64 + (lane & 15);
  const int brow = wn * 64 + (lane & 15);
  const int kq = (lane >> 4) * 16;     // byte offset of this lane's k-block
  int aoff[2][4], boff[2][4];
#pragma unroll
  for (int ks = 0; ks < 2; ++ks)
#pragma unroll
    for (int i = 0; i < 4; ++i) {
      int ra = arow + i * 16;
      int kb = ks * 64 + kq;
      aoff[ks][i] = ra * 128 + (kb ^ ((ra & 7) << 4));
      int rb = brow + i * 16;
      boff[ks][i] = 16384 + rb * 128 + (kb ^ ((rb & 7) << 4));
    }

  for (int kk = 0; kk < 100; ++kk) {
    const int tap = kk >> 2, cic = kk & 3;
    const int dy = tap / 5 - 2, dx = tap % 5 - 2;
    const int offA = ((dy * PW + dx) * 256 + cic * 64) * 2;   // bytes
    const int offB = (tap * 65536 + cic * 64) * 2;            // bytes
#pragma unroll
    for (int l = 0; l < 4; ++l) {
      gload16(baseA[l] + offA, smem + (wv * 4 + l) * 1024);
      gload16(baseB[l] + offB, smem + 16384 + (wv * 4 + l) * 1024);
    }
    __syncthreads();   // drains vmcnt: tiles resident
#pragma unroll
    for (int ks = 0; ks < 2; ++ks) {
      bf16x8 af[4], bfr[4];
#pragma unroll
      for (int i = 0; i < 4; ++i) af[i] = *(const bf16x8*)(smem + aoff[ks][i]);
#pragma unroll
      for (int j = 0; j < 4; ++j) bfr[j] = *(const bf16x8*)(smem + boff[ks][j]);
#pragma unroll
      for (int i = 0; i < 4; ++i)
#pragma unroll
        for (int j = 0; j < 4; ++j)
          acc[i][j] = __builtin_amdgcn_mfma_f32_16x16x32_bf16(af[i], bfr[j], acc[i][j], 0, 0, 0);
    }
    __syncthreads();   // all reads done before next stage overwrites
  }

  // epilogue: C/D layout col=lane&15 (n), row=(lane>>4)*4+reg (m)
  const long ybase = (long)m0 * 256 + n0;
#pragma unroll
  for (int i = 0; i < 4; ++i) {
    int mloc = wm * 64 + i * 16 + (lane >> 4) * 4;
#pragma unroll
    for (int j = 0; j < 4; ++j) {
      int nloc = wn * 64 + j * 16 + (lane & 15);
#pragma unroll
      for (int r = 0; r < 4; ++r)
        y[ybase + (long)(mloc + r) * 256 + nloc] = f2bf(acc[i][j][r]);
    }
  }
}

// ---------------- IDWT: y bf16 NHWC [B,H2,W2,256] (+next_ll fp32 NCHW) -> out fp32 NCHW [B,64,2H2,2W2]
__global__ void k_idwt(const u16* __restrict__ y, const float* __restrict__ nll,
                       float* __restrict__ out, const float* __restrict__ bias,
                       int B_, int H2, int W2) {
  int idx = blockIdx.x * blockDim.x + threadIdx.x;
  int W2h = W2 >> 1;
  int total = B_ * 64 * H2 * W2h;
  if (idx >= total) return;
  int w2h = idx % W2h; int t2 = idx / W2h;
  int h2 = t2 % H2; t2 /= H2;
  int c = t2 % 64; int b = t2 / 64;
  int w2 = w2h * 2;
  long ybase = (((long)b * H2 + h2) * W2 + w2) * 256 + 4 * c;
  ushort4 q0 = *(const ushort4*)(y + ybase);
  ushort4 q1 = *(const ushort4*)(y + ybase + 256);
  float llv0 = bf2f(q0.x), lh0 = bf2f(q0.y), hl0 = bf2f(q0.z), hh0 = bf2f(q0.w);
  float llv1 = bf2f(q1.x), lh1 = bf2f(q1.y), hl1 = bf2f(q1.z), hh1 = bf2f(q1.w);
  if (nll) {
    float2 nv = *(const float2*)(nll + (((long)(b * 64 + c) * H2 + h2) * W2 + w2));
    llv0 += nv.x; llv1 += nv.y;
  }
  float bv = bias ? bias[c] : 0.f;
  float a0 = 0.5f * (llv0 + lh0 + hl0 + hh0) + bv;
  float b0 = 0.5f * (llv0 + lh0 - hl0 - hh0) + bv;
  float c0 = 0.5f * (llv0 - lh0 + hl0 - hh0) + bv;
  float d0 = 0.5f * (llv0 - lh0 - hl0 + hh0) + bv;
  float a1 = 0.5f * (llv1 + lh1 + hl1 + hh1) + bv;
  float b1 = 0.5f * (llv1 + lh1 - hl1 - hh1) + bv;
  float c1 = 0.5f * (llv1 - lh1 + hl1 - hh1) + bv;
  float d1 = 0.5f * (llv1 - lh1 - hl1 + hh1) + bv;
  long obase = (((long)(b * 64 + c) * (2 * H2) + 2 * h2) * (2 * W2)) + 2 * w2;
  *(float4*)(out + obase)             = make_float4(a0, b0, a1, b1);
  *(float4*)(out + obase + 2 * W2)    = make_float4(c0, d0, c1, d1);
}

// ---------------- workspace layout (bytes) ----------------
constexpr size_t WBF_SZ1 = 25ull * 256 * 256 * 2;             // 3,276,800
constexpr size_t OFF_WBF = 0;
constexpr size_t OFF_S0  = 3 * WBF_SZ1;                       // 9,830,400
constexpr size_t S0_SZ   = 8ull * 132 * 132 * 256 * 2;        // 71,368,704
// sub-region inside S0, valid after conv0 has consumed s0:
constexpr size_t REL_S1 = 0;
constexpr size_t S1_SZ  = 8ull * 68 * 68 * 256 * 2;           // 18,939,904
constexpr size_t REL_L1 = REL_S1 + S1_SZ;
constexpr size_t L1_SZ  = 8ull * 64 * 64 * 64 * 4;            // 8,388,608
constexpr size_t REL_S2 = REL_L1 + L1_SZ;
constexpr size_t S2_SZ  = 8ull * 36 * 36 * 256 * 2;           // 5,308,416
constexpr size_t REL_Y1 = REL_S2 + S2_SZ;
constexpr size_t Y1_SZ  = 8ull * 64 * 64 * 256 * 2;           // 16,777,216
constexpr size_t REL_Y2 = REL_Y1 + Y1_SZ;
constexpr size_t Y2_SZ  = 8ull * 32 * 32 * 256 * 2;           // 4,194,304
constexpr size_t REL_N2 = REL_Y2 + Y2_SZ;
constexpr size_t N2_SZ  = 8ull * 64 * 64 * 64 * 4;            // 8,388,608
constexpr size_t REL_L2 = REL_N2 + N2_SZ;                     // 61,997,056 (+2MB <= S0_SZ)
constexpr size_t OFF_L0 = OFF_S0 + S0_SZ;                     // 81,199,104
constexpr size_t L0_SZ  = 8ull * 64 * 128 * 128 * 4;          // 33,554,432 (n1 aliases this)
constexpr size_t OFF_Y0 = OFF_L0 + L0_SZ;                     // 114,753,536
constexpr size_t Y0_SZ  = 8ull * 128 * 128 * 256 * 2;         // 67,108,864
// total required: 181,862,400 bytes

extern "C" void kernel_launch(void* const* d_in, const int* in_sizes, int n_in,
                              void* d_out, int out_size, void* d_ws, size_t ws_size,
                              hipStream_t stream) {
  const float* x    = (const float*)d_in[0];
  const float* w0   = (const float*)d_in[1];
  const float* w1   = (const float*)d_in[2];
  const float* w2   = (const float*)d_in[3];
  const float* bias = (const float*)d_in[4];
  float* out = (float*)d_out;
  char* ws = (char*)d_ws;

  u16* wbf0 = (u16*)(ws + OFF_WBF);
  u16* wbf1 = (u16*)(ws + OFF_WBF + WBF_SZ1);
  u16* wbf2 = (u16*)(ws + OFF_WBF + 2 * WBF_SZ1);
  u16* s0 = (u16*)(ws + OFF_S0);
  u16* s1 = (u16*)(ws + OFF_S0 + REL_S1);
  float* l1 = (float*)(ws + OFF_S0 + REL_L1);
  u16* s2 = (u16*)(ws + OFF_S0 + REL_S2);
  u16* y1 = (u16*)(ws + OFF_S0 + REL_Y1);
  u16* y2 = (u16*)(ws + OFF_S0 + REL_Y2);
  float* n2 = (float*)(ws + OFF_S0 + REL_N2);
  float* l2 = (float*)(ws + OFF_S0 + REL_L2);
  float* l0 = (float*)(ws + OFF_L0);
  float* n1 = (float*)(ws + OFF_L0);   // aliases l0 (dead after dwt1)
  u16* y0 = (u16*)(ws + OFF_Y0);

  // weights -> [tap][co][ci] bf16
  k_wtrans<<<256, 256, 0, stream>>>(w0, wbf0);
  k_wtrans<<<256, 256, 0, stream>>>(w1, wbf1);
  k_wtrans<<<256, 256, 0, stream>>>(w2, wbf2);

  // level 0
  (void)hipMemsetAsync(s0, 0, S0_SZ, stream);                       // zero borders
  k_dwt<<<16384, 256, 0, stream>>>(x, s0, l0, 8, 128, 128);
  k_conv<<<dim3(1024, 2), 256, 0, stream>>>(s0, wbf0, y0, 128, 128);

  // s0 region is free now; zero borders for s1/s2 sub-buffers
  (void)hipMemsetAsync(s1, 0, S1_SZ, stream);
  (void)hipMemsetAsync(s2, 0, S2_SZ, stream);

  // level 1
  k_dwt<<<4096, 256, 0, stream>>>(l0, s1, l1, 8, 64, 64);
  k_conv<<<dim3(256, 2), 256, 0, stream>>>(s1, wbf1, y1, 64, 64);

  // level 2
  k_dwt<<<1024, 256, 0, stream>>>(l1, s2, l2, 8, 32, 32);
  k_conv<<<dim3(64, 2), 256, 0, stream>>>(s2, wbf2, y2, 32, 32);

  // reconstruction
  k_idwt<<<1024, 256, 0, stream>>>(y2, nullptr, n2, nullptr, 8, 32, 32);
  k_idwt<<<4096, 256, 0, stream>>>(y1, n2, n1, nullptr, 8, 64, 64);
  k_idwt<<<16384, 256, 0, stream>>>(y0, n1, out, bias, 8, 128, 128);
}

// Round 2
// 790.254 us; speedup vs baseline: 1.1657x; 1.1657x over previous
//
#include <hip/hip_runtime.h>

// WTConv2d: 3-level Haar DWT -> 5x5 conv (256ch) per level -> IDWT pyramid + bias.
// Convs as implicit GEMM with bf16 MFMA 16x16x32, padded-NHWC input (no bounds checks),
// global_load_lds(16B) staging with source-side XOR swizzle.
// Levels 0,1: deep-pipelined kernel (3-buffer LDS, counted vmcnt(6), setprio, XCD swizzle).

typedef unsigned short u16;
typedef __attribute__((ext_vector_type(8))) __bf16 bf16x8;
typedef __attribute__((ext_vector_type(4))) float f32x4;

__device__ __forceinline__ u16 f2bf(float f) {
  union { float f; unsigned u; } v; v.f = f;
  unsigned r = v.u + 0x7fffu + ((v.u >> 16) & 1u);   // RNE
  return (u16)(r >> 16);
}
__device__ __forceinline__ float bf2f(u16 u) {
  union { unsigned u; float f; } v; v.u = ((unsigned)u) << 16;
  return v.f;
}

typedef const unsigned int __attribute__((address_space(1)))* gas1_t;
typedef unsigned int __attribute__((address_space(3)))* gas3_t;
__device__ __forceinline__ void gload16(const void* g, void* l) {
  __builtin_amdgcn_global_load_lds((gas1_t)g, (gas3_t)l, 16, 0, 0);
}

// ---------------- weight transform: OIHW fp32 -> [tap][co][ci] bf16 ----------------
__global__ void k_wtrans(const float* __restrict__ w, u16* __restrict__ wb) {
  int co = blockIdx.x;           // 256
  int ci = threadIdx.x;          // 256
  const float* src = w + ((long)co * 256 + ci) * 25;
  float v[25];
#pragma unroll
  for (int tp = 0; tp < 25; ++tp) v[tp] = src[tp];
#pragma unroll
  for (int tp = 0; tp < 25; ++tp)
    wb[((long)tp * 256 + co) * 256 + ci] = f2bf(v[tp]);
}

// ---------------- DWT: fp32 NCHW [B,64,2H2,2W2] -> stacked bf16 padded NHWC + ll fp32 ----
__global__ void k_dwt(const float* __restrict__ in, u16* __restrict__ st,
                      float* __restrict__ ll, int B_, int H2, int W2) {
  int idx = blockIdx.x * blockDim.x + threadIdx.x;
  int W2h = W2 >> 1;
  int total = B_ * 64 * H2 * W2h;
  if (idx >= total) return;
  int w2h = idx % W2h; int t2 = idx / W2h;
  int h2 = t2 % H2; t2 /= H2;
  int c = t2 % 64; int b = t2 / 64;
  int w2 = w2h * 2;
  const float* r0 = in + (((long)(b * 64 + c) * (2 * H2) + 2 * h2) * (2 * W2)) + 2 * w2;
  const float* r1 = r0 + 2 * W2;
  float4 tp = *(const float4*)r0;   // a0 b0 a1 b1
  float4 bt = *(const float4*)r1;   // c0 d0 c1 d1
  float ll0 = 0.5f * (tp.x + tp.y + bt.x + bt.y);
  float lh0 = 0.5f * (tp.x + tp.y - bt.x - bt.y);
  float hl0 = 0.5f * (tp.x - tp.y + bt.x - bt.y);
  float hh0 = 0.5f * (tp.x - tp.y - bt.x + bt.y);
  float ll1 = 0.5f * (tp.z + tp.w + bt.z + bt.w);
  float lh1 = 0.5f * (tp.z + tp.w - bt.z - bt.w);
  float hl1 = 0.5f * (tp.z - tp.w + bt.z - bt.w);
  float hh1 = 0.5f * (tp.z - tp.w - bt.z + bt.w);
  long sbase = (((long)b * (H2 + 4) + (h2 + 2)) * (W2 + 4) + (w2 + 2)) * 256 + 4 * c;
  *(ushort4*)(st + sbase)       = make_ushort4(f2bf(ll0), f2bf(lh0), f2bf(hl0), f2bf(hh0));
  *(ushort4*)(st + sbase + 256) = make_ushort4(f2bf(ll1), f2bf(lh1), f2bf(hl1), f2bf(hh1));
  long lbase = (((long)(b * 64 + c) * H2) + h2) * W2 + w2;
  *(float2*)(ll + lbase) = make_float2(ll0, ll1);
}

// ---------------- pipelined conv implicit GEMM (levels 0,1) ----------------
// BM=128 x BN=256 tile, BK=64, 8 waves (2M x 4N, wave tile 64x64), 3-buffer LDS.
// st: padded NHWC bf16 [B][H2+4][W2+4][256]; wt: [25][256][256]; y: [B*H2*W2][256] bf16.
__global__ __launch_bounds__(512, 1) void k_conv_p(
    const u16* __restrict__ st, const u16* __restrict__ wt, u16* __restrict__ y,
    int H2, int W2) {
  __shared__ __align__(16) char smem[147456];   // 3 bufs x (A 16K + B 32K)
  const int t = threadIdx.x;
  const int lane = t & 63;
  const int wv = t >> 6;          // 0..7
  const int wm = wv >> 2;         // 0..1 (m half)
  const int wn = wv & 3;          // 0..3 (n quarter)
  const int nwg = gridDim.x;
  const int bid = blockIdx.x;
  const int lb = (bid & 7) * (nwg >> 3) + (bid >> 3);   // XCD-chunked (nwg % 8 == 0)
  const int m0 = lb * 128;
  const int PW = W2 + 4;

  // ---- staging source pointers (per-thread; source-side XOR swizzle) ----
  const int trow = t >> 3;                       // 0..63: row within a 64-row unit
  const int srcci = ((t & 7) ^ (trow & 7)) * 8;  // swizzled 8-elem chunk
  const char* baseA[2];
  const char* baseB[4];
#pragma unroll
  for (int h = 0; h < 2; ++h) {
    int m = m0 + h * 64 + trow;
    int w = m % W2; int q = m / W2;
    int hh = q % H2; int b = q / H2;
    long sp = ((long)(b * (H2 + 4) + hh + 2) * PW + (w + 2));
    baseA[h] = (const char*)(st + sp * 256 + srcci);
  }
#pragma unroll
  for (int u = 0; u < 4; ++u) {
    int n = u * 64 + trow;
    baseB[u] = (const char*)(wt + (long)n * 256 + srcci);
  }

  f32x4 acc[4][4];
#pragma unroll
  for (int i = 0; i < 4; ++i)
#pragma unroll
    for (int j = 0; j < 4; ++j) acc[i][j] = f32x4{0.f, 0.f, 0.f, 0.f};

  // ---- LDS fragment read byte offsets (match staged swizzle) ----
  const int kq = (lane >> 4) * 16;
  int aoff[2][4], boff[2][4];
#pragma unroll
  for (int ks = 0; ks < 2; ++ks)
#pragma unroll
    for (int i = 0; i < 4; ++i) {
      int ra = wm * 64 + i * 16 + (lane & 15);
      int kb = ks * 64 + kq;
      aoff[ks][i] = ra * 128 + (kb ^ ((ra & 7) << 4));
      int rb = wn * 64 + i * 16 + (lane & 15);
      boff[ks][i] = 16384 + rb * 128 + (kb ^ ((rb & 7) << 4));
    }

  auto stage_a = [&](int kt) {   // units A0, A1, B0 of K-tile kt
    int tap = kt >> 2, cic = kt & 3;
    int dy = tap / 5 - 2, dx = tap % 5 - 2;
    long offA = ((long)(dy * PW + dx) * 256 + cic * 64) * 2;
    long offB = ((long)tap * 65536 + cic * 64) * 2;
    char* lb2 = smem + (kt % 3) * 49152 + wv * 1024;
    gload16(baseA[0] + offA, lb2);
    gload16(baseA[1] + offA, lb2 + 8192);
    gload16(baseB[0] + offB, lb2 + 16384);
  };
  auto stage_b = [&](int kt) {   // units B1, B2, B3
    int tap = kt >> 2, cic = kt & 3;
    long offB = ((long)tap * 65536 + cic * 64) * 2;
    char* lb2 = smem + (kt % 3) * 49152 + wv * 1024;
    gload16(baseB[1] + offB, lb2 + 24576);
    gload16(baseB[2] + offB, lb2 + 32768);
    gload16(baseB[3] + offB, lb2 + 40960);
  };

  // prologue: stage kt0, kt1; guarantee kt0 resident (kt1 stays in flight)
  stage_a(0); stage_b(0);
  stage_a(1); stage_b(1);
  asm volatile("s_waitcnt vmcnt(6)" ::: "memory");
  __builtin_amdgcn_s_barrier();

  for (int kt = 0; kt < 100; ++kt) {
    const char* la = smem + (kt % 3) * 49152;
    const bool st2 = (kt + 2) < 100;
    // ---------- phase 0 : ks=0 ----------
    bf16x8 af[4], bfr[4];
#pragma unroll
    for (int i = 0; i < 4; ++i) af[i] = *(const bf16x8*)(la + aoff[0][i]);
#pragma unroll
    for (int j = 0; j < 4; ++j) bfr[j] = *(const bf16x8*)(la + boff[0][j]);
    if (st2) stage_a(kt + 2);
    __builtin_amdgcn_s_barrier();
    asm volatile("s_waitcnt lgkmcnt(0)" ::: "memory");
    __builtin_amdgcn_sched_barrier(0);
    __builtin_amdgcn_s_setprio(1);
#pragma unroll
    for (int i = 0; i < 4; ++i)
#pragma unroll
      for (int j = 0; j < 4; ++j)
        acc[i][j] = __builtin_amdgcn_mfma_f32_16x16x32_bf16(af[i], bfr[j], acc[i][j], 0, 0, 0);
    __builtin_amdgcn_s_setprio(0);
    __builtin_amdgcn_s_barrier();
    // ---------- phase 1 : ks=1 ----------
#pragma unroll
    for (int i = 0; i < 4; ++i) af[i] = *(const bf16x8*)(la + aoff[1][i]);
#pragma unroll
    for (int j = 0; j < 4; ++j) bfr[j] = *(const bf16x8*)(la + boff[1][j]);
    if (st2) stage_b(kt + 2);
    __builtin_amdgcn_s_barrier();
    asm volatile("s_waitcnt lgkmcnt(0)" ::: "memory");
    __builtin_amdgcn_sched_barrier(0);
    __builtin_amdgcn_s_setprio(1);
#pragma unroll
    for (int i = 0; i < 4; ++i)
#pragma unroll
      for (int j = 0; j < 4; ++j)
        acc[i][j] = __builtin_amdgcn_mfma_f32_16x16x32_bf16(af[i], bfr[j], acc[i][j], 0, 0, 0);
    __builtin_amdgcn_s_setprio(0);
    // boundary: kt+1 must be resident after this barrier; kt+2 (6 loads) stays in flight
    if (st2) {
      asm volatile("s_waitcnt vmcnt(6)" ::: "memory");
    } else if (kt + 1 < 100) {
      asm volatile("s_waitcnt vmcnt(0)" ::: "memory");
    }
    __builtin_amdgcn_s_barrier();
  }

  // epilogue: C/D layout col=lane&15 (n), row=(lane>>4)*4+reg (m)
#pragma unroll
  for (int i = 0; i < 4; ++i) {
    int mloc = m0 + wm * 64 + i * 16 + (lane >> 4) * 4;
#pragma unroll
    for (int j = 0; j < 4; ++j) {
      int nloc = wn * 64 + j * 16 + (lane & 15);
#pragma unroll
      for (int r = 0; r < 4; ++r)
        y[(long)(mloc + r) * 256 + nloc] = f2bf(acc[i][j][r]);
    }
  }
}

// ---------------- simple conv (level 2: only 64 m-blocks) ----------------
__global__ __launch_bounds__(256) void k_conv(
    const u16* __restrict__ st, const u16* __restrict__ wt, u16* __restrict__ y,
    int H2, int W2) {
  __shared__ __align__(16) char smem[32768];   // A: [0,16K), B: [16K,32K)
  const int t = threadIdx.x;
  const int lane = t & 63;
  const int wv = t >> 6;
  const int wm = wv >> 1, wn = wv & 1;
  const int m0 = blockIdx.x * 128;
  const int n0 = blockIdx.y * 128;
  const int PW = W2 + 4;
  const int lsub = lane & 7;
  const int lrow8 = lane >> 3;
  const int srcci = (lsub ^ lrow8) * 8;

  const char* baseA[4];
  const char* baseB[4];
#pragma unroll
  for (int l = 0; l < 4; ++l) {
    int ml = (wv * 4 + l) * 8 + lrow8;
    int m = m0 + ml;
    int w = m % W2;
    int q = m / W2;
    int h = q % H2;
    int b = q / H2;
    long sp = ((long)(b * (H2 + 4) + h + 2) * PW + (w + 2));
    baseA[l] = (const char*)(st + sp * 256 + srcci);
    int nl = n0 + (wv * 4 + l) * 8 + lrow8;
    baseB[l] = (const char*)(wt + (long)nl * 256 + srcci);
  }

  f32x4 acc[4][4];
#pragma unroll
  for (int i = 0; i < 4; ++i)
#pragma unroll
    for (int j = 0; j < 4; ++j) acc[i][j] = f32x4{0.f, 0.f, 0.f, 0.f};

  const int arow = wm * 64 + (lane & 15);
  const int brow = wn * 64 + (lane & 15);
  const int kq = (lane >> 4) * 16;
  int aoff[2][4], boff[2][4];
#pragma unroll
  for (int ks = 0; ks < 2; ++ks)
#pragma unroll
    for (int i = 0; i < 4; ++i) {
      int ra = arow + i * 16;
      int kb = ks * 64 + kq;
      aoff[ks][i] = ra * 128 + (kb ^ ((ra & 7) << 4));
      int rb = brow + i * 16;
      boff[ks][i] = 16384 + rb * 128 + (kb ^ ((rb & 7) << 4));
    }

  for (int kk = 0; kk < 100; ++kk) {
    const int tap = kk >> 2, cic = kk & 3;
    const int dy = tap / 5 - 2, dx = tap % 5 - 2;
    const int offA = ((dy * PW + dx) * 256 + cic * 64) * 2;
    const int offB = (tap * 65536 + cic * 64) * 2;
#pragma unroll
    for (int l = 0; l < 4; ++l) {
      gload16(baseA[l] + offA, smem + (wv * 4 + l) * 1024);
      gload16(baseB[l] + offB, smem + 16384 + (wv * 4 + l) * 1024);
    }
    __syncthreads();
#pragma unroll
    for (int ks = 0; ks < 2; ++ks) {
      bf16x8 af[4], bfr[4];
#pragma unroll
      for (int i = 0; i < 4; ++i) af[i] = *(const bf16x8*)(smem + aoff[ks][i]);
#pragma unroll
      for (int j = 0; j < 4; ++j) bfr[j] = *(const bf16x8*)(smem + boff[ks][j]);
#pragma unroll
      for (int i = 0; i < 4; ++i)
#pragma unroll
        for (int j = 0; j < 4; ++j)
          acc[i][j] = __builtin_amdgcn_mfma_f32_16x16x32_bf16(af[i], bfr[j], acc[i][j], 0, 0, 0);
    }
    __syncthreads();
  }

  const long ybase = (long)m0 * 256 + n0;
#pragma unroll
  for (int i = 0; i < 4; ++i) {
    int mloc = wm * 64 + i * 16 + (lane >> 4) * 4;
#pragma unroll
    for (int j = 0; j < 4; ++j) {
      int nloc = wn * 64 + j * 16 + (lane & 15);
#pragma unroll
      for (int r = 0; r < 4; ++r)
        y[ybase + (long)(mloc + r) * 256 + nloc] = f2bf(acc[i][j][r]);
    }
  }
}

// ---------------- IDWT ----------------
__global__ void k_idwt(const u16* __restrict__ y, const float* __restrict__ nll,
                       float* __restrict__ out, const float* __restrict__ bias,
                       int B_, int H2, int W2) {
  int idx = blockIdx.x * blockDim.x + threadIdx.x;
  int W2h = W2 >> 1;
  int total = B_ * 64 * H2 * W2h;
  if (idx >= total) return;
  int w2h = idx % W2h; int t2 = idx / W2h;
  int h2 = t2 % H2; t2 /= H2;
  int c = t2 % 64; int b = t2 / 64;
  int w2 = w2h * 2;
  long ybase = (((long)b * H2 + h2) * W2 + w2) * 256 + 4 * c;
  ushort4 q0 = *(const ushort4*)(y + ybase);
  ushort4 q1 = *(const ushort4*)(y + ybase + 256);
  float llv0 = bf2f(q0.x), lh0 = bf2f(q0.y), hl0 = bf2f(q0.z), hh0 = bf2f(q0.w);
  float llv1 = bf2f(q1.x), lh1 = bf2f(q1.y), hl1 = bf2f(q1.z), hh1 = bf2f(q1.w);
  if (nll) {
    float2 nv = *(const float2*)(nll + (((long)(b * 64 + c) * H2 + h2) * W2 + w2));
    llv0 += nv.x; llv1 += nv.y;
  }
  float bv = bias ? bias[c] : 0.f;
  float a0 = 0.5f * (llv0 + lh0 + hl0 + hh0) + bv;
  float b0 = 0.5f * (llv0 + lh0 - hl0 - hh0) + bv;
  float c0 = 0.5f * (llv0 - lh0 + hl0 - hh0) + bv;
  float d0 = 0.5f * (llv0 - lh0 - hl0 + hh0) + bv;
  float a1 = 0.5f * (llv1 + lh1 + hl1 + hh1) + bv;
  float b1 = 0.5f * (llv1 + lh1 - hl1 - hh1) + bv;
  float c1 = 0.5f * (llv1 - lh1 + hl1 - hh1) + bv;
  float d1 = 0.5f * (llv1 - lh1 - hl1 + hh1) + bv;
  long obase = (((long)(b * 64 + c) * (2 * H2) + 2 * h2) * (2 * W2)) + 2 * w2;
  *(float4*)(out + obase)             = make_float4(a0, b0, a1, b1);
  *(float4*)(out + obase + 2 * W2)    = make_float4(c0, d0, c1, d1);
}

// ---------------- workspace layout (bytes) ----------------
constexpr size_t WBF_SZ1 = 25ull * 256 * 256 * 2;
constexpr size_t OFF_WBF = 0;
constexpr size_t OFF_S0  = 3 * WBF_SZ1;
constexpr size_t S0_SZ   = 8ull * 132 * 132 * 256 * 2;
constexpr size_t REL_S1 = 0;
constexpr size_t S1_SZ  = 8ull * 68 * 68 * 256 * 2;
constexpr size_t REL_L1 = REL_S1 + S1_SZ;
constexpr size_t L1_SZ  = 8ull * 64 * 64 * 64 * 4;
constexpr size_t REL_S2 = REL_L1 + L1_SZ;
constexpr size_t S2_SZ  = 8ull * 36 * 36 * 256 * 2;
constexpr size_t REL_Y1 = REL_S2 + S2_SZ;
constexpr size_t Y1_SZ  = 8ull * 64 * 64 * 256 * 2;
constexpr size_t REL_Y2 = REL_Y1 + Y1_SZ;
constexpr size_t Y2_SZ  = 8ull * 32 * 32 * 256 * 2;
constexpr size_t REL_N2 = REL_Y2 + Y2_SZ;
constexpr size_t N2_SZ  = 8ull * 64 * 64 * 64 * 4;
constexpr size_t REL_L2 = REL_N2 + N2_SZ;
constexpr size_t OFF_L0 = OFF_S0 + S0_SZ;
constexpr size_t L0_SZ  = 8ull * 64 * 128 * 128 * 4;
constexpr size_t OFF_Y0 = OFF_L0 + L0_SZ;
constexpr size_t Y0_SZ  = 8ull * 128 * 128 * 256 * 2;

extern "C" void kernel_launch(void* const* d_in, const int* in_sizes, int n_in,
                              void* d_out, int out_size, void* d_ws, size_t ws_size,
                              hipStream_t stream) {
  const float* x    = (const float*)d_in[0];
  const float* w0   = (const float*)d_in[1];
  const float* w1   = (const float*)d_in[2];
  const float* w2   = (const float*)d_in[3];
  const float* bias = (const float*)d_in[4];
  float* out = (float*)d_out;
  char* ws = (char*)d_ws;

  u16* wbf0 = (u16*)(ws + OFF_WBF);
  u16* wbf1 = (u16*)(ws + OFF_WBF + WBF_SZ1);
  u16* wbf2 = (u16*)(ws + OFF_WBF + 2 * WBF_SZ1);
  u16* s0 = (u16*)(ws + OFF_S0);
  u16* s1 = (u16*)(ws + OFF_S0 + REL_S1);
  float* l1 = (float*)(ws + OFF_S0 + REL_L1);
  u16* s2 = (u16*)(ws + OFF_S0 + REL_S2);
  u16* y1 = (u16*)(ws + OFF_S0 + REL_Y1);
  u16* y2 = (u16*)(ws + OFF_S0 + REL_Y2);
  float* n2 = (float*)(ws + OFF_S0 + REL_N2);
  float* l2 = (float*)(ws + OFF_S0 + REL_L2);
  float* l0 = (float*)(ws + OFF_L0);
  float* n1 = (float*)(ws + OFF_L0);   // aliases l0 (dead after dwt1)
  u16* y0 = (u16*)(ws + OFF_Y0);

  k_wtrans<<<256, 256, 0, stream>>>(w0, wbf0);
  k_wtrans<<<256, 256, 0, stream>>>(w1, wbf1);
  k_wtrans<<<256, 256, 0, stream>>>(w2, wbf2);

  // level 0
  (void)hipMemsetAsync(s0, 0, S0_SZ, stream);
  k_dwt<<<16384, 256, 0, stream>>>(x, s0, l0, 8, 128, 128);
  k_conv_p<<<1024, 512, 0, stream>>>(s0, wbf0, y0, 128, 128);

  (void)hipMemsetAsync(s1, 0, S1_SZ, stream);
  (void)hipMemsetAsync(s2, 0, S2_SZ, stream);

  // level 1
  k_dwt<<<4096, 256, 0, stream>>>(l0, s1, l1, 8, 64, 64);
  k_conv_p<<<256, 512, 0, stream>>>(s1, wbf1, y1, 64, 64);

  // level 2
  k_dwt<<<1024, 256, 0, stream>>>(l1, s2, l2, 8, 32, 32);
  k_conv<<<dim3(64, 2), 256, 0, stream>>>(s2, wbf2, y2, 32, 32);

  // reconstruction
  k_idwt<<<1024, 256, 0, stream>>>(y2, nullptr, n2, nullptr, 8, 32, 32);
  k_idwt<<<4096, 256, 0, stream>>>(y1, n2, n1, nullptr, 8, 64, 64);
  k_idwt<<<16384, 256, 0, stream>>>(y0, n1, out, bias, 8, 128, 128);
}

// Round 3
// 741.566 us; speedup vs baseline: 1.2422x; 1.0657x over previous
//
#include <hip/hip_runtime.h>

// WTConv2d: 3-level Haar DWT -> 5x5 conv (256ch) per level -> IDWT pyramid + bias.
// Level 0: 256x256-tile 8-phase pipelined implicit-GEMM conv (counted vmcnt(4)).
// Level 1: 128x256 3-buffer pipelined conv. Level 2: simple 128x128 conv.

typedef unsigned short u16;
typedef __attribute__((ext_vector_type(8))) __bf16 bf16x8;
typedef __attribute__((ext_vector_type(4))) float f32x4;

__device__ __forceinline__ u16 f2bf(float f) {
  union { float f; unsigned u; } v; v.f = f;
  unsigned r = v.u + 0x7fffu + ((v.u >> 16) & 1u);   // RNE
  return (u16)(r >> 16);
}
__device__ __forceinline__ float bf2f(u16 u) {
  union { unsigned u; float f; } v; v.u = ((unsigned)u) << 16;
  return v.f;
}

typedef const unsigned int __attribute__((address_space(1)))* gas1_t;
typedef unsigned int __attribute__((address_space(3)))* gas3_t;
__device__ __forceinline__ void gload16(const void* g, void* l) {
  __builtin_amdgcn_global_load_lds((gas1_t)g, (gas3_t)l, 16, 0, 0);
}

// ---------------- weight transform: OIHW fp32 -> [tap][co][ci] bf16 ----------------
__global__ void k_wtrans(const float* __restrict__ w, u16* __restrict__ wb) {
  int co = blockIdx.x;
  int ci = threadIdx.x;
  const float* src = w + ((long)co * 256 + ci) * 25;
  float v[25];
#pragma unroll
  for (int tp = 0; tp < 25; ++tp) v[tp] = src[tp];
#pragma unroll
  for (int tp = 0; tp < 25; ++tp)
    wb[((long)tp * 256 + co) * 256 + ci] = f2bf(v[tp]);
}

// ---------------- border zero (pad frame of stacked buffer) ----------------
__global__ void k_border(u16* __restrict__ st, int B_, int H2, int W2) {
  int PW = W2 + 4;
  int npix = 4 * PW + 4 * H2;
  int gid = blockIdx.x * blockDim.x + threadIdx.x;
  int pid = gid >> 6, lane = gid & 63;
  if (pid >= B_ * npix) return;
  int b = pid / npix, p = pid % npix;
  int row, col;
  if (p < 2 * PW) { row = p / PW; col = p % PW; }
  else if (p < 4 * PW) { int q = p - 2 * PW; row = H2 + 2 + q / PW; col = q % PW; }
  else { int q = p - 4 * PW; row = 2 + (q >> 2); int c4 = q & 3; col = (c4 < 2) ? c4 : W2 + c4; }
  long base = (((long)b * (H2 + 4) + row) * PW + col) * 256 + lane * 4;
  *(ushort4*)(st + base) = make_ushort4(0, 0, 0, 0);
}

// ---------------- DWT: fp32 NCHW -> stacked bf16 padded NHWC + ll fp32 ----------------
__global__ void k_dwt(const float* __restrict__ in, u16* __restrict__ st,
                      float* __restrict__ ll, int B_, int H2, int W2) {
  int idx = blockIdx.x * blockDim.x + threadIdx.x;
  int W2h = W2 >> 1;
  int total = B_ * 64 * H2 * W2h;
  if (idx >= total) return;
  int w2h = idx % W2h; int t2 = idx / W2h;
  int h2 = t2 % H2; t2 /= H2;
  int c = t2 % 64; int b = t2 / 64;
  int w2 = w2h * 2;
  const float* r0 = in + (((long)(b * 64 + c) * (2 * H2) + 2 * h2) * (2 * W2)) + 2 * w2;
  const float* r1 = r0 + 2 * W2;
  float4 tp = *(const float4*)r0;
  float4 bt = *(const float4*)r1;
  float ll0 = 0.5f * (tp.x + tp.y + bt.x + bt.y);
  float lh0 = 0.5f * (tp.x + tp.y - bt.x - bt.y);
  float hl0 = 0.5f * (tp.x - tp.y + bt.x - bt.y);
  float hh0 = 0.5f * (tp.x - tp.y - bt.x + bt.y);
  float ll1 = 0.5f * (tp.z + tp.w + bt.z + bt.w);
  float lh1 = 0.5f * (tp.z + tp.w - bt.z - bt.w);
  float hl1 = 0.5f * (tp.z - tp.w + bt.z - bt.w);
  float hh1 = 0.5f * (tp.z - tp.w - bt.z + bt.w);
  long sbase = (((long)b * (H2 + 4) + (h2 + 2)) * (W2 + 4) + (w2 + 2)) * 256 + 4 * c;
  *(ushort4*)(st + sbase)       = make_ushort4(f2bf(ll0), f2bf(lh0), f2bf(hl0), f2bf(hh0));
  *(ushort4*)(st + sbase + 256) = make_ushort4(f2bf(ll1), f2bf(lh1), f2bf(hl1), f2bf(hh1));
  long lbase = (((long)(b * 64 + c) * H2) + h2) * W2 + w2;
  *(float2*)(ll + lbase) = make_float2(ll0, ll1);
}

// ---------------- 8-phase 256x256 conv (level 0) ----------------
// Quadrant phases per K-tile (BK=64): ph1 (mh0,nh0), ph2 (mh1,nh0), ph3 (mh0,nh1), ph4 (mh1,nh1).
// Stage units (8KB, 1 gload/thread): ph1: B-u01(kt+1,alt), ph2: B-u23(kt+1,alt),
// ph3: A-u01(kt+2,cur), ph4: A-u23(kt+2,cur). vmcnt(4) once per K-tile (tail: 0).
__global__ __launch_bounds__(512, 1) void k_conv8(
    const u16* __restrict__ st, const u16* __restrict__ wt, u16* __restrict__ y,
    int H2, int W2) {
  __shared__ __align__(16) char smem[131072];   // 2 bufs x (A 32K + B 32K)
  const int t = threadIdx.x;
  const int lane = t & 63;
  const int wv = t >> 6;
  const int wm = wv >> 2, wn = wv & 3;          // 2M x 4N waves; wave tile 128x64
  const int nwg = gridDim.x;
  const int bid = blockIdx.x;
  const int lb = (bid & 7) * (nwg >> 3) + (bid >> 3);  // XCD-chunked (nwg%8==0)
  const int m0 = lb * 256;
  const int PW = W2 + 4;

  // staging sources (source-side XOR swizzle)
  const int trow = t >> 3;
  const int srcci = ((t & 7) ^ (trow & 7)) * 8;
  const char* baseA[4];
#pragma unroll
  for (int u = 0; u < 4; ++u) {
    int m = m0 + u * 64 + trow;
    int w = m % W2; int q = m / W2;
    int hh = q % H2; int b = q / H2;
    long sp = ((long)(b * (H2 + 4) + hh + 2) * PW + (w + 2));
    baseA[u] = (const char*)(st + sp * 256 + srcci);
  }
  const char* baseB0 = (const char*)(wt + trow * 256 + srcci);

  f32x4 acc[8][4];
#pragma unroll
  for (int i = 0; i < 8; ++i)
#pragma unroll
    for (int j = 0; j < 4; ++j) acc[i][j] = f32x4{0.f, 0.f, 0.f, 0.f};

  // LDS read bases (swizzle: row&7 == lane&7 for all fragment rows)
  const int kq = (lane >> 4) * 16;
  const int sw = (lane & 7) << 4;
  const int kx0 = (kq) ^ sw;
  const int kx1 = (64 + kq) ^ sw;
  const int aBase = (wm * 128 + (lane & 15)) * 128;
  const int bBase = 32768 + (wn * 64 + (lane & 15)) * 128;

  auto stageA = [&](int kt, char* dst, int up) {
    int tap = kt >> 2, cic = kt & 3;
    int dy = tap / 5 - 2, dx = tap % 5 - 2;
    long off = ((long)(dy * PW + dx) * 256 + cic * 64) * 2;
#pragma unroll
    for (int u = up * 2; u < up * 2 + 2; ++u)
      gload16(baseA[u] + off, dst + u * 8192 + wv * 1024);
  };
  auto stageB = [&](int kt, char* dst, int up) {
    int tap = kt >> 2, cic = kt & 3;
    long off = ((long)tap * 65536 + cic * 64) * 2;
#pragma unroll
    for (int u = up * 2; u < up * 2 + 2; ++u)
      gload16(baseB0 + u * 32768 + off, dst + 32768 + u * 8192 + wv * 1024);
  };

#define QMFMA(mh, nh)                                                              \
  _Pragma("unroll") for (int i = 0; i < 4; ++i)                                    \
  _Pragma("unroll") for (int jj = 0; jj < 2; ++jj)                                 \
  _Pragma("unroll") for (int ks = 0; ks < 2; ++ks)                                 \
    acc[(mh)*4 + i][(nh)*2 + jj] = __builtin_amdgcn_mfma_f32_16x16x32_bf16(        \
        af[mh][i][ks], bfr[jj][ks], acc[(mh)*4 + i][(nh)*2 + jj], 0, 0, 0);

  // prologue: kt0 fully + kt1's A; kt0 resident, kt1-A (4 loads) in flight
  stageA(0, smem, 0); stageA(0, smem, 1);
  stageB(0, smem, 0); stageB(0, smem, 1);
  stageA(1, smem + 65536, 0); stageA(1, smem + 65536, 1);
  asm volatile("s_waitcnt vmcnt(4)" ::: "memory");
  __builtin_amdgcn_s_barrier();

  for (int kt = 0; kt < 100; ++kt) {
    char* bufp = smem + (kt & 1) * 65536;
    char* altp = smem + ((kt & 1) ^ 1) * 65536;
    bf16x8 af[2][4][2], bfr[2][2];
    // ---- ph1: (mh0, nh0); stage B-u01(kt+1 -> alt) ----
#pragma unroll
    for (int i = 0; i < 4; ++i) {
      af[0][i][0] = *(const bf16x8*)(bufp + aBase + i * 2048 + kx0);
      af[0][i][1] = *(const bf16x8*)(bufp + aBase + i * 2048 + kx1);
    }
#pragma unroll
    for (int jj = 0; jj < 2; ++jj) {
      bfr[jj][0] = *(const bf16x8*)(bufp + bBase + jj * 2048 + kx0);
      bfr[jj][1] = *(const bf16x8*)(bufp + bBase + jj * 2048 + kx1);
    }
    if (kt + 1 < 100) stageB(kt + 1, altp, 0);
    __builtin_amdgcn_s_barrier();
    asm volatile("s_waitcnt lgkmcnt(0)" ::: "memory");
    __builtin_amdgcn_sched_barrier(0);
    __builtin_amdgcn_s_setprio(1);
    QMFMA(0, 0)
    __builtin_amdgcn_s_setprio(0);
    __builtin_amdgcn_s_barrier();
    // ---- ph2: (mh1, nh0); stage B-u23(kt+1 -> alt) ----
#pragma unroll
    for (int i = 0; i < 4; ++i) {
      af[1][i][0] = *(const bf16x8*)(bufp + aBase + (4 + i) * 2048 + kx0);
      af[1][i][1] = *(const bf16x8*)(bufp + aBase + (4 + i) * 2048 + kx1);
    }
    if (kt + 1 < 100) stageB(kt + 1, altp, 1);
    __builtin_amdgcn_s_barrier();
    asm volatile("s_waitcnt lgkmcnt(0)" ::: "memory");
    __builtin_amdgcn_sched_barrier(0);
    __builtin_amdgcn_s_setprio(1);
    QMFMA(1, 0)
    __builtin_amdgcn_s_setprio(0);
    __builtin_amdgcn_s_barrier();
    // ---- ph3: (mh0, nh1); stage A-u01(kt+2 -> cur) ----
#pragma unroll
    for (int jj = 0; jj < 2; ++jj) {
      bfr[jj][0] = *(const bf16x8*)(bufp + bBase + (2 + jj) * 2048 + kx0);
      bfr[jj][1] = *(const bf16x8*)(bufp + bBase + (2 + jj) * 2048 + kx1);
    }
    if (kt + 2 < 100) stageA(kt + 2, bufp, 0);
    __builtin_amdgcn_s_barrier();
    asm volatile("s_waitcnt lgkmcnt(0)" ::: "memory");
    __builtin_amdgcn_sched_barrier(0);
    __builtin_amdgcn_s_setprio(1);
    QMFMA(0, 1)
    __builtin_amdgcn_s_setprio(0);
    __builtin_amdgcn_s_barrier();
    // ---- ph4: (mh1, nh1); stage A-u23(kt+2 -> cur); counted vmcnt ----
    if (kt + 2 < 100) stageA(kt + 2, bufp, 1);
    __builtin_amdgcn_s_barrier();
    __builtin_amdgcn_s_setprio(1);
    QMFMA(1, 1)
    __builtin_amdgcn_s_setprio(0);
    if (kt < 98) { asm volatile("s_waitcnt vmcnt(4)" ::: "memory"); }
    else if (kt == 98) { asm volatile("s_waitcnt vmcnt(0)" ::: "memory"); }
    __builtin_amdgcn_s_barrier();
  }
#undef QMFMA

  // epilogue
#pragma unroll
  for (int i = 0; i < 8; ++i) {
    int mloc = m0 + wm * 128 + i * 16 + (lane >> 4) * 4;
#pragma unroll
    for (int j = 0; j < 4; ++j) {
      int nloc = wn * 64 + j * 16 + (lane & 15);
#pragma unroll
      for (int r = 0; r < 4; ++r)
        y[(long)(mloc + r) * 256 + nloc] = f2bf(acc[i][j][r]);
    }
  }
}

// ---------------- pipelined conv (level 1): BM=128 x BN=256, 3-buffer ----------------
__global__ __launch_bounds__(512, 1) void k_conv_p(
    const u16* __restrict__ st, const u16* __restrict__ wt, u16* __restrict__ y,
    int H2, int W2) {
  __shared__ __align__(16) char smem[147456];
  const int t = threadIdx.x;
  const int lane = t & 63;
  const int wv = t >> 6;
  const int wm = wv >> 2;
  const int wn = wv & 3;
  const int nwg = gridDim.x;
  const int bid = blockIdx.x;
  const int lb = (bid & 7) * (nwg >> 3) + (bid >> 3);
  const int m0 = lb * 128;
  const int PW = W2 + 4;

  const int trow = t >> 3;
  const int srcci = ((t & 7) ^ (trow & 7)) * 8;
  const char* baseA[2];
  const char* baseB[4];
#pragma unroll
  for (int h = 0; h < 2; ++h) {
    int m = m0 + h * 64 + trow;
    int w = m % W2; int q = m / W2;
    int hh = q % H2; int b = q / H2;
    long sp = ((long)(b * (H2 + 4) + hh + 2) * PW + (w + 2));
    baseA[h] = (const char*)(st + sp * 256 + srcci);
  }
#pragma unroll
  for (int u = 0; u < 4; ++u) {
    int n = u * 64 + trow;
    baseB[u] = (const char*)(wt + (long)n * 256 + srcci);
  }

  f32x4 acc[4][4];
#pragma unroll
  for (int i = 0; i < 4; ++i)
#pragma unroll
    for (int j = 0; j < 4; ++j) acc[i][j] = f32x4{0.f, 0.f, 0.f, 0.f};

  const int kq = (lane >> 4) * 16;
  int aoff[2][4], boff[2][4];
#pragma unroll
  for (int ks = 0; ks < 2; ++ks)
#pragma unroll
    for (int i = 0; i < 4; ++i) {
      int ra = wm * 64 + i * 16 + (lane & 15);
      int kb = ks * 64 + kq;
      aoff[ks][i] = ra * 128 + (kb ^ ((ra & 7) << 4));
      int rb = wn * 64 + i * 16 + (lane & 15);
      boff[ks][i] = 16384 + rb * 128 + (kb ^ ((rb & 7) << 4));
    }

  auto stage_a = [&](int kt) {
    int tap = kt >> 2, cic = kt & 3;
    int dy = tap / 5 - 2, dx = tap % 5 - 2;
    long offA = ((long)(dy * PW + dx) * 256 + cic * 64) * 2;
    long offB = ((long)tap * 65536 + cic * 64) * 2;
    char* lb2 = smem + (kt % 3) * 49152 + wv * 1024;
    gload16(baseA[0] + offA, lb2);
    gload16(baseA[1] + offA, lb2 + 8192);
    gload16(baseB[0] + offB, lb2 + 16384);
  };
  auto stage_b = [&](int kt) {
    int tap = kt >> 2, cic = kt & 3;
    long offB = ((long)tap * 65536 + cic * 64) * 2;
    char* lb2 = smem + (kt % 3) * 49152 + wv * 1024;
    gload16(baseB[1] + offB, lb2 + 24576);
    gload16(baseB[2] + offB, lb2 + 32768);
    gload16(baseB[3] + offB, lb2 + 40960);
  };

  stage_a(0); stage_b(0);
  stage_a(1); stage_b(1);
  asm volatile("s_waitcnt vmcnt(6)" ::: "memory");
  __builtin_amdgcn_s_barrier();

  for (int kt = 0; kt < 100; ++kt) {
    const char* la = smem + (kt % 3) * 49152;
    const bool st2 = (kt + 2) < 100;
    bf16x8 af[4], bfr[4];
#pragma unroll
    for (int i = 0; i < 4; ++i) af[i] = *(const bf16x8*)(la + aoff[0][i]);
#pragma unroll
    for (int j = 0; j < 4; ++j) bfr[j] = *(const bf16x8*)(la + boff[0][j]);
    if (st2) stage_a(kt + 2);
    __builtin_amdgcn_s_barrier();
    asm volatile("s_waitcnt lgkmcnt(0)" ::: "memory");
    __builtin_amdgcn_sched_barrier(0);
    __builtin_amdgcn_s_setprio(1);
#pragma unroll
    for (int i = 0; i < 4; ++i)
#pragma unroll
      for (int j = 0; j < 4; ++j)
        acc[i][j] = __builtin_amdgcn_mfma_f32_16x16x32_bf16(af[i], bfr[j], acc[i][j], 0, 0, 0);
    __builtin_amdgcn_s_setprio(0);
    __builtin_amdgcn_s_barrier();
#pragma unroll
    for (int i = 0; i < 4; ++i) af[i] = *(const bf16x8*)(la + aoff[1][i]);
#pragma unroll
    for (int j = 0; j < 4; ++j) bfr[j] = *(const bf16x8*)(la + boff[1][j]);
    if (st2) stage_b(kt + 2);
    __builtin_amdgcn_s_barrier();
    asm volatile("s_waitcnt lgkmcnt(0)" ::: "memory");
    __builtin_amdgcn_sched_barrier(0);
    __builtin_amdgcn_s_setprio(1);
#pragma unroll
    for (int i = 0; i < 4; ++i)
#pragma unroll
      for (int j = 0; j < 4; ++j)
        acc[i][j] = __builtin_amdgcn_mfma_f32_16x16x32_bf16(af[i], bfr[j], acc[i][j], 0, 0, 0);
    __builtin_amdgcn_s_setprio(0);
    if (st2) {
      asm volatile("s_waitcnt vmcnt(6)" ::: "memory");
    } else if (kt + 1 < 100) {
      asm volatile("s_waitcnt vmcnt(0)" ::: "memory");
    }
    __builtin_amdgcn_s_barrier();
  }

#pragma unroll
  for (int i = 0; i < 4; ++i) {
    int mloc = m0 + wm * 64 + i * 16 + (lane >> 4) * 4;
#pragma unroll
    for (int j = 0; j < 4; ++j) {
      int nloc = wn * 64 + j * 16 + (lane & 15);
#pragma unroll
      for (int r = 0; r < 4; ++r)
        y[(long)(mloc + r) * 256 + nloc] = f2bf(acc[i][j][r]);
    }
  }
}

// ---------------- simple conv (level 2) ----------------
__global__ __launch_bounds__(256) void k_conv(
    const u16* __restrict__ st, const u16* __restrict__ wt, u16* __restrict__ y,
    int H2, int W2) {
  __shared__ __align__(16) char smem[32768];
  const int t = threadIdx.x;
  const int lane = t & 63;
  const int wv = t >> 6;
  const int wm = wv >> 1, wn = wv & 1;
  const int m0 = blockIdx.x * 128;
  const int n0 = blockIdx.y * 128;
  const int PW = W2 + 4;
  const int lsub = lane & 7;
  const int lrow8 = lane >> 3;
  const int srcci = (lsub ^ lrow8) * 8;

  const char* baseA[4];
  const char* baseB[4];
#pragma unroll
  for (int l = 0; l < 4; ++l) {
    int ml = (wv * 4 + l) * 8 + lrow8;
    int m = m0 + ml;
    int w = m % W2;
    int q = m / W2;
    int h = q % H2;
    int b = q / H2;
    long sp = ((long)(b * (H2 + 4) + h + 2) * PW + (w + 2));
    baseA[l] = (const char*)(st + sp * 256 + srcci);
    int nl = n0 + (wv * 4 + l) * 8 + lrow8;
    baseB[l] = (const char*)(wt + (long)nl * 256 + srcci);
  }

  f32x4 acc[4][4];
#pragma unroll
  for (int i = 0; i < 4; ++i)
#pragma unroll
    for (int j = 0; j < 4; ++j) acc[i][j] = f32x4{0.f, 0.f, 0.f, 0.f};

  const int arow = wm * 64 + (lane & 15);
  const int brow = wn * 64 + (lane & 15);
  const int kq = (lane >> 4) * 16;
  int aoff[2][4], boff[2][4];
#pragma unroll
  for (int ks = 0; ks < 2; ++ks)
#pragma unroll
    for (int i = 0; i < 4; ++i) {
      int ra = arow + i * 16;
      int kb = ks * 64 + kq;
      aoff[ks][i] = ra * 128 + (kb ^ ((ra & 7) << 4));
      int rb = brow + i * 16;
      boff[ks][i] = 16384 + rb * 128 + (kb ^ ((rb & 7) << 4));
    }

  for (int kk = 0; kk < 100; ++kk) {
    const int tap = kk >> 2, cic = kk & 3;
    const int dy = tap / 5 - 2, dx = tap % 5 - 2;
    const int offA = ((dy * PW + dx) * 256 + cic * 64) * 2;
    const int offB = (tap * 65536 + cic * 64) * 2;
#pragma unroll
    for (int l = 0; l < 4; ++l) {
      gload16(baseA[l] + offA, smem + (wv * 4 + l) * 1024);
      gload16(baseB[l] + offB, smem + 16384 + (wv * 4 + l) * 1024);
    }
    __syncthreads();
#pragma unroll
    for (int ks = 0; ks < 2; ++ks) {
      bf16x8 af[4], bfr[4];
#pragma unroll
      for (int i = 0; i < 4; ++i) af[i] = *(const bf16x8*)(smem + aoff[ks][i]);
#pragma unroll
      for (int j = 0; j < 4; ++j) bfr[j] = *(const bf16x8*)(smem + boff[ks][j]);
#pragma unroll
      for (int i = 0; i < 4; ++i)
#pragma unroll
        for (int j = 0; j < 4; ++j)
          acc[i][j] = __builtin_amdgcn_mfma_f32_16x16x32_bf16(af[i], bfr[j], acc[i][j], 0, 0, 0);
    }
    __syncthreads();
  }

  const long ybase = (long)m0 * 256 + n0;
#pragma unroll
  for (int i = 0; i < 4; ++i) {
    int mloc = wm * 64 + i * 16 + (lane >> 4) * 4;
#pragma unroll
    for (int j = 0; j < 4; ++j) {
      int nloc = wn * 64 + j * 16 + (lane & 15);
#pragma unroll
      for (int r = 0; r < 4; ++r)
        y[ybase + (long)(mloc + r) * 256 + nloc] = f2bf(acc[i][j][r]);
    }
  }
}

// ---------------- IDWT ----------------
__global__ void k_idwt(const u16* __restrict__ y, const float* __restrict__ nll,
                       float* __restrict__ out, const float* __restrict__ bias,
                       int B_, int H2, int W2) {
  int idx = blockIdx.x * blockDim.x + threadIdx.x;
  int W2h = W2 >> 1;
  int total = B_ * 64 * H2 * W2h;
  if (idx >= total) return;
  int w2h = idx % W2h; int t2 = idx / W2h;
  int h2 = t2 % H2; t2 /= H2;
  int c = t2 % 64; int b = t2 / 64;
  int w2 = w2h * 2;
  long ybase = (((long)b * H2 + h2) * W2 + w2) * 256 + 4 * c;
  ushort4 q0 = *(const ushort4*)(y + ybase);
  ushort4 q1 = *(const ushort4*)(y + ybase + 256);
  float llv0 = bf2f(q0.x), lh0 = bf2f(q0.y), hl0 = bf2f(q0.z), hh0 = bf2f(q0.w);
  float llv1 = bf2f(q1.x), lh1 = bf2f(q1.y), hl1 = bf2f(q1.z), hh1 = bf2f(q1.w);
  if (nll) {
    float2 nv = *(const float2*)(nll + (((long)(b * 64 + c) * H2 + h2) * W2 + w2));
    llv0 += nv.x; llv1 += nv.y;
  }
  float bv = bias ? bias[c] : 0.f;
  float a0 = 0.5f * (llv0 + lh0 + hl0 + hh0) + bv;
  float b0 = 0.5f * (llv0 + lh0 - hl0 - hh0) + bv;
  float c0 = 0.5f * (llv0 - lh0 + hl0 - hh0) + bv;
  float d0 = 0.5f * (llv0 - lh0 - hl0 + hh0) + bv;
  float a1 = 0.5f * (llv1 + lh1 + hl1 + hh1) + bv;
  float b1 = 0.5f * (llv1 + lh1 - hl1 - hh1) + bv;
  float c1 = 0.5f * (llv1 - lh1 + hl1 - hh1) + bv;
  float d1 = 0.5f * (llv1 - lh1 - hl1 + hh1) + bv;
  long obase = (((long)(b * 64 + c) * (2 * H2) + 2 * h2) * (2 * W2)) + 2 * w2;
  *(float4*)(out + obase)          = make_float4(a0, b0, a1, b1);
  *(float4*)(out + obase + 2 * W2) = make_float4(c0, d0, c1, d1);
}

// ---------------- workspace layout (bytes) ----------------
constexpr size_t WBF_SZ1 = 25ull * 256 * 256 * 2;
constexpr size_t OFF_WBF = 0;
constexpr size_t OFF_S0  = 3 * WBF_SZ1;
constexpr size_t S0_SZ   = 8ull * 132 * 132 * 256 * 2;
constexpr size_t REL_S1 = 0;
constexpr size_t S1_SZ  = 8ull * 68 * 68 * 256 * 2;
constexpr size_t REL_L1 = REL_S1 + S1_SZ;
constexpr size_t L1_SZ  = 8ull * 64 * 64 * 64 * 4;
constexpr size_t REL_S2 = REL_L1 + L1_SZ;
constexpr size_t S2_SZ  = 8ull * 36 * 36 * 256 * 2;
constexpr size_t REL_Y1 = REL_S2 + S2_SZ;
constexpr size_t Y1_SZ  = 8ull * 64 * 64 * 256 * 2;
constexpr size_t REL_Y2 = REL_Y1 + Y1_SZ;
constexpr size_t Y2_SZ  = 8ull * 32 * 32 * 256 * 2;
constexpr size_t REL_N2 = REL_Y2 + Y2_SZ;
constexpr size_t N2_SZ  = 8ull * 64 * 64 * 64 * 4;
constexpr size_t REL_L2 = REL_N2 + N2_SZ;
constexpr size_t OFF_L0 = OFF_S0 + S0_SZ;
constexpr size_t L0_SZ  = 8ull * 64 * 128 * 128 * 4;
constexpr size_t OFF_Y0 = OFF_L0 + L0_SZ;
constexpr size_t Y0_SZ  = 8ull * 128 * 128 * 256 * 2;

extern "C" void kernel_launch(void* const* d_in, const int* in_sizes, int n_in,
                              void* d_out, int out_size, void* d_ws, size_t ws_size,
                              hipStream_t stream) {
  const float* x    = (const float*)d_in[0];
  const float* w0   = (const float*)d_in[1];
  const float* w1   = (const float*)d_in[2];
  const float* w2   = (const float*)d_in[3];
  const float* bias = (const float*)d_in[4];
  float* out = (float*)d_out;
  char* ws = (char*)d_ws;

  u16* wbf0 = (u16*)(ws + OFF_WBF);
  u16* wbf1 = (u16*)(ws + OFF_WBF + WBF_SZ1);
  u16* wbf2 = (u16*)(ws + OFF_WBF + 2 * WBF_SZ1);
  u16* s0 = (u16*)(ws + OFF_S0);
  u16* s1 = (u16*)(ws + OFF_S0 + REL_S1);
  float* l1 = (float*)(ws + OFF_S0 + REL_L1);
  u16* s2 = (u16*)(ws + OFF_S0 + REL_S2);
  u16* y1 = (u16*)(ws + OFF_S0 + REL_Y1);
  u16* y2 = (u16*)(ws + OFF_S0 + REL_Y2);
  float* n2 = (float*)(ws + OFF_S0 + REL_N2);
  float* l2 = (float*)(ws + OFF_S0 + REL_L2);
  float* l0 = (float*)(ws + OFF_L0);
  float* n1 = (float*)(ws + OFF_L0);   // aliases l0 (dead after dwt1)
  u16* y0 = (u16*)(ws + OFF_Y0);

  k_wtrans<<<256, 256, 0, stream>>>(w0, wbf0);
  k_wtrans<<<256, 256, 0, stream>>>(w1, wbf1);
  k_wtrans<<<256, 256, 0, stream>>>(w2, wbf2);

  // level 0 (border pixels: 8*(4*132+4*128)=8320 -> grid 2080)
  k_border<<<2080, 256, 0, stream>>>(s0, 8, 128, 128);
  k_dwt<<<16384, 256, 0, stream>>>(x, s0, l0, 8, 128, 128);
  k_conv8<<<512, 512, 0, stream>>>(s0, wbf0, y0, 128, 128);

  // borders for s1 (8*(4*68+4*64)=4224 -> 1056), s2 (8*(4*36+4*32)=2176 -> 544)
  k_border<<<1056, 256, 0, stream>>>(s1, 8, 64, 64);
  k_border<<<544, 256, 0, stream>>>(s2, 8, 32, 32);

  // level 1
  k_dwt<<<4096, 256, 0, stream>>>(l0, s1, l1, 8, 64, 64);
  k_conv_p<<<256, 512, 0, stream>>>(s1, wbf1, y1, 64, 64);

  // level 2
  k_dwt<<<1024, 256, 0, stream>>>(l1, s2, l2, 8, 32, 32);
  k_conv<<<dim3(64, 2), 256, 0, stream>>>(s2, wbf2, y2, 32, 32);

  // reconstruction
  k_idwt<<<1024, 256, 0, stream>>>(y2, nullptr, n2, nullptr, 8, 32, 32);
  k_idwt<<<4096, 256, 0, stream>>>(y1, n2, n1, nullptr, 8, 64, 64);
  k_idwt<<<16384, 256, 0, stream>>>(y0, n1, out, bias, 8, 128, 128);
}

// Round 4
// 715.327 us; speedup vs baseline: 1.2878x; 1.0367x over previous
//
#include <hip/hip_runtime.h>

// WTConv2d: 3-level Haar DWT -> 5x5 conv (256ch) per level -> IDWT pyramid + bias.
// Level 0: 256x256-tile conv, 4 phases/K-tile, cross-phase ds_read pipelining
// (reads issued one phase before consumption), counted lgkmcnt/vmcnt, 4 barriers/K-tile.
// Level 1: 128x256 3-buffer pipelined conv. Level 2: simple 128x128 conv.

typedef unsigned short u16;
typedef __attribute__((ext_vector_type(8))) __bf16 bf16x8;
typedef __attribute__((ext_vector_type(4))) float f32x4;

__device__ __forceinline__ u16 f2bf(float f) {
  union { float f; unsigned u; } v; v.f = f;
  unsigned r = v.u + 0x7fffu + ((v.u >> 16) & 1u);   // RNE
  return (u16)(r >> 16);
}
__device__ __forceinline__ float bf2f(u16 u) {
  union { unsigned u; float f; } v; v.u = ((unsigned)u) << 16;
  return v.f;
}

typedef const unsigned int __attribute__((address_space(1)))* gas1_t;
typedef unsigned int __attribute__((address_space(3)))* gas3_t;
__device__ __forceinline__ void gload16(const void* g, void* l) {
  __builtin_amdgcn_global_load_lds((gas1_t)g, (gas3_t)l, 16, 0, 0);
}

// ---------------- weight transform: OIHW fp32 -> [tap][co][ci] bf16 ----------------
__global__ void k_wtrans(const float* __restrict__ w, u16* __restrict__ wb) {
  int co = blockIdx.x;
  int ci = threadIdx.x;
  const float* src = w + ((long)co * 256 + ci) * 25;
  float v[25];
#pragma unroll
  for (int tp = 0; tp < 25; ++tp) v[tp] = src[tp];
#pragma unroll
  for (int tp = 0; tp < 25; ++tp)
    wb[((long)tp * 256 + co) * 256 + ci] = f2bf(v[tp]);
}

// ---------------- border zero (pad frame of stacked buffer) ----------------
__global__ void k_border(u16* __restrict__ st, int B_, int H2, int W2) {
  int PW = W2 + 4;
  int npix = 4 * PW + 4 * H2;
  int gid = blockIdx.x * blockDim.x + threadIdx.x;
  int pid = gid >> 6, lane = gid & 63;
  if (pid >= B_ * npix) return;
  int b = pid / npix, p = pid % npix;
  int row, col;
  if (p < 2 * PW) { row = p / PW; col = p % PW; }
  else if (p < 4 * PW) { int q = p - 2 * PW; row = H2 + 2 + q / PW; col = q % PW; }
  else { int q = p - 4 * PW; row = 2 + (q >> 2); int c4 = q & 3; col = (c4 < 2) ? c4 : W2 + c4; }
  long base = (((long)b * (H2 + 4) + row) * PW + col) * 256 + lane * 4;
  *(ushort4*)(st + base) = make_ushort4(0, 0, 0, 0);
}

// ---------------- DWT: fp32 NCHW -> stacked bf16 padded NHWC + ll fp32 ----------------
__global__ void k_dwt(const float* __restrict__ in, u16* __restrict__ st,
                      float* __restrict__ ll, int B_, int H2, int W2) {
  int idx = blockIdx.x * blockDim.x + threadIdx.x;
  int W2h = W2 >> 1;
  int total = B_ * 64 * H2 * W2h;
  if (idx >= total) return;
  int w2h = idx % W2h; int t2 = idx / W2h;
  int h2 = t2 % H2; t2 /= H2;
  int c = t2 % 64; int b = t2 / 64;
  int w2 = w2h * 2;
  const float* r0 = in + (((long)(b * 64 + c) * (2 * H2) + 2 * h2) * (2 * W2)) + 2 * w2;
  const float* r1 = r0 + 2 * W2;
  float4 tp = *(const float4*)r0;
  float4 bt = *(const float4*)r1;
  float ll0 = 0.5f * (tp.x + tp.y + bt.x + bt.y);
  float lh0 = 0.5f * (tp.x + tp.y - bt.x - bt.y);
  float hl0 = 0.5f * (tp.x - tp.y + bt.x - bt.y);
  float hh0 = 0.5f * (tp.x - tp.y - bt.x + bt.y);
  float ll1 = 0.5f * (tp.z + tp.w + bt.z + bt.w);
  float lh1 = 0.5f * (tp.z + tp.w - bt.z - bt.w);
  float hl1 = 0.5f * (tp.z - tp.w + bt.z - bt.w);
  float hh1 = 0.5f * (tp.z - tp.w - bt.z + bt.w);
  long sbase = (((long)b * (H2 + 4) + (h2 + 2)) * (W2 + 4) + (w2 + 2)) * 256 + 4 * c;
  *(ushort4*)(st + sbase)       = make_ushort4(f2bf(ll0), f2bf(lh0), f2bf(hl0), f2bf(hh0));
  *(ushort4*)(st + sbase + 256) = make_ushort4(f2bf(ll1), f2bf(lh1), f2bf(hl1), f2bf(hh1));
  long lbase = (((long)(b * 64 + c) * H2) + h2) * W2 + w2;
  *(float2*)(ll + lbase) = make_float2(ll0, ll1);
}

// ---------------- 256x256 conv, cross-phase-pipelined reads (level 0) ----------------
// Quadrant order per K-tile: ph1 (0,0), ph2 (1,0), ph3 (1,1), ph4 (0,1).
// Reads: ph1 pre: af1(kt); ph2 post: b23(kt); ph4 post: af0(kt+1)+b01(kt+1).
// Stages: ph1 B01(kt+1), ph2 B23(kt+1), ph3 A_H0(kt+2), ph4 A_H1(kt+2).
// Gates: lgkmcnt(8) at ph1, lgkmcnt(0) after; vmcnt(4) once per K-tile (tail 0).
__global__ __launch_bounds__(512, 1) void k_conv8(
    const u16* __restrict__ st, const u16* __restrict__ wt, u16* __restrict__ y,
    int H2, int W2) {
  __shared__ __align__(16) char smem[131072];   // 2 bufs x (A 32K + B 32K)
  const int t = threadIdx.x;
  const int lane = t & 63;
  const int wv = t >> 6;
  const int wm = wv >> 2, wn = wv & 3;          // 2M x 4N waves; wave tile 128x64
  const int nwg = gridDim.x;
  const int bid = blockIdx.x;
  const int lb = (bid & 7) * (nwg >> 3) + (bid >> 3);  // XCD-chunked (nwg%8==0)
  const int m0 = lb * 256;
  const int PW = W2 + 4;

  // staging sources (source-side XOR swizzle)
  const int trow = t >> 3;
  const int srcci = ((t & 7) ^ (trow & 7)) * 8;
  const char* baseA[4];
#pragma unroll
  for (int u = 0; u < 4; ++u) {
    int m = m0 + u * 64 + trow;
    int w = m % W2; int q = m / W2;
    int hh = q % H2; int b = q / H2;
    long sp = ((long)(b * (H2 + 4) + hh + 2) * PW + (w + 2));
    baseA[u] = (const char*)(st + sp * 256 + srcci);
  }
  const char* baseB0 = (const char*)(wt + trow * 256 + srcci);

  f32x4 acc[8][4];
#pragma unroll
  for (int i = 0; i < 8; ++i)
#pragma unroll
    for (int j = 0; j < 4; ++j) acc[i][j] = f32x4{0.f, 0.f, 0.f, 0.f};

  // LDS read bases (swizzle: frag row & 7 == lane & 7)
  const int kq = (lane >> 4) * 16;
  const int sw = (lane & 7) << 4;
  const int kx0 = kq ^ sw;
  const int kx1 = (64 + kq) ^ sw;
  const int aBase = (wm * 128 + (lane & 15)) * 128;
  const int bBase = 32768 + (wn * 64 + (lane & 15)) * 128;

  bf16x8 a0[4][2], a1[4][2], bb[2][2];

  auto stageA = [&](long off, char* dst, int half) {   // half0: units 0,2; half1: 1,3
    gload16(baseA[half] + off, dst + half * 8192 + wv * 1024);
    gload16(baseA[2 + half] + off, dst + (2 + half) * 8192 + wv * 1024);
  };
  auto stageB = [&](long off, char* dst, int half) {   // half0: units 0,1; half1: 2,3
    gload16(baseB0 + (2 * half) * 32768 + off, dst + 32768 + (2 * half) * 8192 + wv * 1024);
    gload16(baseB0 + (2 * half + 1) * 32768 + off, dst + 32768 + (2 * half + 1) * 8192 + wv * 1024);
  };

#define LDA0(P) { _Pragma("unroll") for (int i = 0; i < 4; ++i) { \
    a0[i][0] = *(const bf16x8*)((P) + aBase + i * 2048 + kx0);    \
    a0[i][1] = *(const bf16x8*)((P) + aBase + i * 2048 + kx1); } }
#define LDA1(P) { _Pragma("unroll") for (int i = 0; i < 4; ++i) {        \
    a1[i][0] = *(const bf16x8*)((P) + aBase + 8192 + i * 2048 + kx0);    \
    a1[i][1] = *(const bf16x8*)((P) + aBase + 8192 + i * 2048 + kx1); } }
#define LDB01(P) { _Pragma("unroll") for (int j = 0; j < 2; ++j) { \
    bb[j][0] = *(const bf16x8*)((P) + bBase + j * 2048 + kx0);     \
    bb[j][1] = *(const bf16x8*)((P) + bBase + j * 2048 + kx1); } }
#define LDB23(P) { _Pragma("unroll") for (int j = 0; j < 2; ++j) {        \
    bb[j][0] = *(const bf16x8*)((P) + bBase + 4096 + j * 2048 + kx0);     \
    bb[j][1] = *(const bf16x8*)((P) + bBase + 4096 + j * 2048 + kx1); } }
#define MM(I0, J0, A)                                                         \
  _Pragma("unroll") for (int i = 0; i < 4; ++i)                               \
  _Pragma("unroll") for (int j = 0; j < 2; ++j)                               \
  _Pragma("unroll") for (int ks = 0; ks < 2; ++ks)                            \
    acc[(I0) + i][(J0) + j] = __builtin_amdgcn_mfma_f32_16x16x32_bf16(        \
        A[i][ks], bb[j][ks], acc[(I0) + i][(J0) + j], 0, 0, 0);

#define KTILE(BUFP, ALTP, STGB, STGA, VMN, OFFB, OFFA)                        \
  { char* bufp_ = (BUFP); char* altp_ = (ALTP);                               \
    /* ph1: (0,0) */                                                          \
    LDA1(bufp_)                                                               \
    if (STGB) stageB((OFFB), altp_, 0);                                       \
    __builtin_amdgcn_s_barrier();                                             \
    asm volatile("s_waitcnt lgkmcnt(8)" ::: "memory");                        \
    __builtin_amdgcn_sched_barrier(0);                                        \
    __builtin_amdgcn_s_setprio(1);                                            \
    MM(0, 0, a0)                                                              \
    __builtin_amdgcn_s_setprio(0);                                            \
    /* ph2: (1,0) */                                                          \
    if (STGB) stageB((OFFB), altp_, 1);                                       \
    __builtin_amdgcn_s_barrier();                                             \
    asm volatile("s_waitcnt lgkmcnt(0)" ::: "memory");                        \
    __builtin_amdgcn_sched_barrier(0);                                        \
    __builtin_amdgcn_s_setprio(1);                                            \
    MM(4, 0, a1)                                                              \
    __builtin_amdgcn_s_setprio(0);                                            \
    __builtin_amdgcn_sched_barrier(0);                                        \
    LDB23(bufp_)                                                              \
    /* ph3: (1,1) */                                                          \
    if (STGA) stageA((OFFA), bufp_, 0);                                       \
    __builtin_amdgcn_s_barrier();                                             \
    asm volatile("s_waitcnt lgkmcnt(0)" ::: "memory");                        \
    __builtin_amdgcn_sched_barrier(0);                                        \
    __builtin_amdgcn_s_setprio(1);                                            \
    MM(4, 2, a1)                                                              \
    __builtin_amdgcn_s_setprio(0);                                            \
    /* ph4: (0,1) */                                                          \
    if (STGA) stageA((OFFA), bufp_, 1);                                       \
    if ((VMN) == 4) { asm volatile("s_waitcnt vmcnt(4)" ::: "memory"); }      \
    else if ((VMN) == 0) { asm volatile("s_waitcnt vmcnt(0)" ::: "memory"); } \
    __builtin_amdgcn_s_barrier();                                             \
    asm volatile("s_waitcnt lgkmcnt(0)" ::: "memory");                        \
    __builtin_amdgcn_sched_barrier(0);                                        \
    __builtin_amdgcn_s_setprio(1);                                            \
    MM(0, 2, a0)                                                              \
    __builtin_amdgcn_s_setprio(0);                                            \
    __builtin_amdgcn_sched_barrier(0);                                        \
    if ((VMN) >= 0) { LDA0(altp_) LDB01(altp_) }                              \
  }

  // uniform incremental tap offsets (bytes)
  const long offA00 = ((long)(-2 * PW - 2)) * 512;   // tap (dy=-2,dx=-2), cic 0
  // prologue: A(0),B(0)->buf0, A(1)->buf1 ; then read af0(0), b01(0)
  stageA(offA00, smem, 0); stageA(offA00, smem, 1);
  stageB(0, smem, 0); stageB(0, smem, 1);
  stageA(offA00 + 128, smem + 65536, 0); stageA(offA00 + 128, smem + 65536, 1);
  asm volatile("s_waitcnt vmcnt(4)" ::: "memory");
  __builtin_amdgcn_s_barrier();
  LDA0(smem) LDB01(smem)

  long offB = 128; int cB = 1;                 // tracks kk = kt+1, starting at 1
  long offA = offA00 + 256; int cA = 2;        // tracks kk = kt+2, starting at 2
  const long aWrap = (long)PW * 512 - 2560;

  for (int kt = 0; kt < 98; ++kt) {
    char* bufp = smem + (kt & 1) * 65536;
    char* altp = smem + ((kt & 1) ^ 1) * 65536;
    KTILE(bufp, altp, 1, 1, 4, offB, offA)
    offB += 128; if (++cB == 4) { cB = 0; offB += 130560; }
    offA += 128; if (++cA == 20) { cA = 0; offA += aWrap; }
  }
  KTILE(smem, smem + 65536, 1, 0, 0, offB, offA)   // kt = 98
  KTILE(smem + 65536, smem, 0, 0, -1, offB, offA)  // kt = 99

#undef KTILE
#undef MM
#undef LDA0
#undef LDA1
#undef LDB01
#undef LDB23

  // epilogue: C/D layout col=lane&15 (n), row=(lane>>4)*4+reg (m)
#pragma unroll
  for (int i = 0; i < 8; ++i) {
    int mloc = m0 + wm * 128 + i * 16 + (lane >> 4) * 4;
#pragma unroll
    for (int j = 0; j < 4; ++j) {
      int nloc = wn * 64 + j * 16 + (lane & 15);
#pragma unroll
      for (int r = 0; r < 4; ++r)
        y[(long)(mloc + r) * 256 + nloc] = f2bf(acc[i][j][r]);
    }
  }
}

// ---------------- pipelined conv (level 1): BM=128 x BN=256, 3-buffer ----------------
__global__ __launch_bounds__(512, 1) void k_conv_p(
    const u16* __restrict__ st, const u16* __restrict__ wt, u16* __restrict__ y,
    int H2, int W2) {
  __shared__ __align__(16) char smem[147456];
  const int t = threadIdx.x;
  const int lane = t & 63;
  const int wv = t >> 6;
  const int wm = wv >> 2;
  const int wn = wv & 3;
  const int nwg = gridDim.x;
  const int bid = blockIdx.x;
  const int lb = (bid & 7) * (nwg >> 3) + (bid >> 3);
  const int m0 = lb * 128;
  const int PW = W2 + 4;

  const int trow = t >> 3;
  const int srcci = ((t & 7) ^ (trow & 7)) * 8;
  const char* baseA[2];
  const char* baseB[4];
#pragma unroll
  for (int h = 0; h < 2; ++h) {
    int m = m0 + h * 64 + trow;
    int w = m % W2; int q = m / W2;
    int hh = q % H2; int b = q / H2;
    long sp = ((long)(b * (H2 + 4) + hh + 2) * PW + (w + 2));
    baseA[h] = (const char*)(st + sp * 256 + srcci);
  }
#pragma unroll
  for (int u = 0; u < 4; ++u) {
    int n = u * 64 + trow;
    baseB[u] = (const char*)(wt + (long)n * 256 + srcci);
  }

  f32x4 acc[4][4];
#pragma unroll
  for (int i = 0; i < 4; ++i)
#pragma unroll
    for (int j = 0; j < 4; ++j) acc[i][j] = f32x4{0.f, 0.f, 0.f, 0.f};

  const int kq = (lane >> 4) * 16;
  int aoff[2][4], boff[2][4];
#pragma unroll
  for (int ks = 0; ks < 2; ++ks)
#pragma unroll
    for (int i = 0; i < 4; ++i) {
      int ra = wm * 64 + i * 16 + (lane & 15);
      int kb = ks * 64 + kq;
      aoff[ks][i] = ra * 128 + (kb ^ ((ra & 7) << 4));
      int rb = wn * 64 + i * 16 + (lane & 15);
      boff[ks][i] = 16384 + rb * 128 + (kb ^ ((rb & 7) << 4));
    }

  auto stage_a = [&](int kt) {
    int tap = kt >> 2, cic = kt & 3;
    int dy = tap / 5 - 2, dx = tap % 5 - 2;
    long offA = ((long)(dy * PW + dx) * 256 + cic * 64) * 2;
    long offB = ((long)tap * 65536 + cic * 64) * 2;
    char* lb2 = smem + (kt % 3) * 49152 + wv * 1024;
    gload16(baseA[0] + offA, lb2);
    gload16(baseA[1] + offA, lb2 + 8192);
    gload16(baseB[0] + offB, lb2 + 16384);
  };
  auto stage_b = [&](int kt) {
    int tap = kt >> 2, cic = kt & 3;
    long offB = ((long)tap * 65536 + cic * 64) * 2;
    char* lb2 = smem + (kt % 3) * 49152 + wv * 1024;
    gload16(baseB[1] + offB, lb2 + 24576);
    gload16(baseB[2] + offB, lb2 + 32768);
    gload16(baseB[3] + offB, lb2 + 40960);
  };

  stage_a(0); stage_b(0);
  stage_a(1); stage_b(1);
  asm volatile("s_waitcnt vmcnt(6)" ::: "memory");
  __builtin_amdgcn_s_barrier();

  for (int kt = 0; kt < 100; ++kt) {
    const char* la = smem + (kt % 3) * 49152;
    const bool st2 = (kt + 2) < 100;
    bf16x8 af[4], bfr[4];
#pragma unroll
    for (int i = 0; i < 4; ++i) af[i] = *(const bf16x8*)(la + aoff[0][i]);
#pragma unroll
    for (int j = 0; j < 4; ++j) bfr[j] = *(const bf16x8*)(la + boff[0][j]);
    if (st2) stage_a(kt + 2);
    __builtin_amdgcn_s_barrier();
    asm volatile("s_waitcnt lgkmcnt(0)" ::: "memory");
    __builtin_amdgcn_sched_barrier(0);
    __builtin_amdgcn_s_setprio(1);
#pragma unroll
    for (int i = 0; i < 4; ++i)
#pragma unroll
      for (int j = 0; j < 4; ++j)
        acc[i][j] = __builtin_amdgcn_mfma_f32_16x16x32_bf16(af[i], bfr[j], acc[i][j], 0, 0, 0);
    __builtin_amdgcn_s_setprio(0);
    __builtin_amdgcn_s_barrier();
#pragma unroll
    for (int i = 0; i < 4; ++i) af[i] = *(const bf16x8*)(la + aoff[1][i]);
#pragma unroll
    for (int j = 0; j < 4; ++j) bfr[j] = *(const bf16x8*)(la + boff[1][j]);
    if (st2) stage_b(kt + 2);
    __builtin_amdgcn_s_barrier();
    asm volatile("s_waitcnt lgkmcnt(0)" ::: "memory");
    __builtin_amdgcn_sched_barrier(0);
    __builtin_amdgcn_s_setprio(1);
#pragma unroll
    for (int i = 0; i < 4; ++i)
#pragma unroll
      for (int j = 0; j < 4; ++j)
        acc[i][j] = __builtin_amdgcn_mfma_f32_16x16x32_bf16(af[i], bfr[j], acc[i][j], 0, 0, 0);
    __builtin_amdgcn_s_setprio(0);
    if (st2) {
      asm volatile("s_waitcnt vmcnt(6)" ::: "memory");
    } else if (kt + 1 < 100) {
      asm volatile("s_waitcnt vmcnt(0)" ::: "memory");
    }
    __builtin_amdgcn_s_barrier();
  }

#pragma unroll
  for (int i = 0; i < 4; ++i) {
    int mloc = m0 + wm * 64 + i * 16 + (lane >> 4) * 4;
#pragma unroll
    for (int j = 0; j < 4; ++j) {
      int nloc = wn * 64 + j * 16 + (lane & 15);
#pragma unroll
      for (int r = 0; r < 4; ++r)
        y[(long)(mloc + r) * 256 + nloc] = f2bf(acc[i][j][r]);
    }
  }
}

// ---------------- simple conv (level 2) ----------------
__global__ __launch_bounds__(256) void k_conv(
    const u16* __restrict__ st, const u16* __restrict__ wt, u16* __restrict__ y,
    int H2, int W2) {
  __shared__ __align__(16) char smem[32768];
  const int t = threadIdx.x;
  const int lane = t & 63;
  const int wv = t >> 6;
  const int wm = wv >> 1, wn = wv & 1;
  const int m0 = blockIdx.x * 128;
  const int n0 = blockIdx.y * 128;
  const int PW = W2 + 4;
  const int lsub = lane & 7;
  const int lrow8 = lane >> 3;
  const int srcci = (lsub ^ lrow8) * 8;

  const char* baseA[4];
  const char* baseB[4];
#pragma unroll
  for (int l = 0; l < 4; ++l) {
    int ml = (wv * 4 + l) * 8 + lrow8;
    int m = m0 + ml;
    int w = m % W2;
    int q = m / W2;
    int h = q % H2;
    int b = q / H2;
    long sp = ((long)(b * (H2 + 4) + h + 2) * PW + (w + 2));
    baseA[l] = (const char*)(st + sp * 256 + srcci);
    int nl = n0 + (wv * 4 + l) * 8 + lrow8;
    baseB[l] = (const char*)(wt + (long)nl * 256 + srcci);
  }

  f32x4 acc[4][4];
#pragma unroll
  for (int i = 0; i < 4; ++i)
#pragma unroll
    for (int j = 0; j < 4; ++j) acc[i][j] = f32x4{0.f, 0.f, 0.f, 0.f};

  const int arow = wm * 64 + (lane & 15);
  const int brow = wn * 64 + (lane & 15);
  const int kq = (lane >> 4) * 16;
  int aoff[2][4], boff[2][4];
#pragma unroll
  for (int ks = 0; ks < 2; ++ks)
#pragma unroll
    for (int i = 0; i < 4; ++i) {
      int ra = arow + i * 16;
      int kb = ks * 64 + kq;
      aoff[ks][i] = ra * 128 + (kb ^ ((ra & 7) << 4));
      int rb = brow + i * 16;
      boff[ks][i] = 16384 + rb * 128 + (kb ^ ((rb & 7) << 4));
    }

  for (int kk = 0; kk < 100; ++kk) {
    const int tap = kk >> 2, cic = kk & 3;
    const int dy = tap / 5 - 2, dx = tap % 5 - 2;
    const int offA = ((dy * PW + dx) * 256 + cic * 64) * 2;
    const int offB = (tap * 65536 + cic * 64) * 2;
#pragma unroll
    for (int l = 0; l < 4; ++l) {
      gload16(baseA[l] + offA, smem + (wv * 4 + l) * 1024);
      gload16(baseB[l] + offB, smem + 16384 + (wv * 4 + l) * 1024);
    }
    __syncthreads();
#pragma unroll
    for (int ks = 0; ks < 2; ++ks) {
      bf16x8 af[4], bfr[4];
#pragma unroll
      for (int i = 0; i < 4; ++i) af[i] = *(const bf16x8*)(smem + aoff[ks][i]);
#pragma unroll
      for (int j = 0; j < 4; ++j) bfr[j] = *(const bf16x8*)(smem + boff[ks][j]);
#pragma unroll
      for (int i = 0; i < 4; ++i)
#pragma unroll
        for (int j = 0; j < 4; ++j)
          acc[i][j] = __builtin_amdgcn_mfma_f32_16x16x32_bf16(af[i], bfr[j], acc[i][j], 0, 0, 0);
    }
    __syncthreads();
  }

  const long ybase = (long)m0 * 256 + n0;
#pragma unroll
  for (int i = 0; i < 4; ++i) {
    int mloc = wm * 64 + i * 16 + (lane >> 4) * 4;
#pragma unroll
    for (int j = 0; j < 4; ++j) {
      int nloc = wn * 64 + j * 16 + (lane & 15);
#pragma unroll
      for (int r = 0; r < 4; ++r)
        y[ybase + (long)(mloc + r) * 256 + nloc] = f2bf(acc[i][j][r]);
    }
  }
}

// ---------------- IDWT ----------------
__global__ void k_idwt(const u16* __restrict__ y, const float* __restrict__ nll,
                       float* __restrict__ out, const float* __restrict__ bias,
                       int B_, int H2, int W2) {
  int idx = blockIdx.x * blockDim.x + threadIdx.x;
  int W2h = W2 >> 1;
  int total = B_ * 64 * H2 * W2h;
  if (idx >= total) return;
  int w2h = idx % W2h; int t2 = idx / W2h;
  int h2 = t2 % H2; t2 /= H2;
  int c = t2 % 64; int b = t2 / 64;
  int w2 = w2h * 2;
  long ybase = (((long)b * H2 + h2) * W2 + w2) * 256 + 4 * c;
  ushort4 q0 = *(const ushort4*)(y + ybase);
  ushort4 q1 = *(const ushort4*)(y + ybase + 256);
  float llv0 = bf2f(q0.x), lh0 = bf2f(q0.y), hl0 = bf2f(q0.z), hh0 = bf2f(q0.w);
  float llv1 = bf2f(q1.x), lh1 = bf2f(q1.y), hl1 = bf2f(q1.z), hh1 = bf2f(q1.w);
  if (nll) {
    float2 nv = *(const float2*)(nll + (((long)(b * 64 + c) * H2 + h2) * W2 + w2));
    llv0 += nv.x; llv1 += nv.y;
  }
  float bv = bias ? bias[c] : 0.f;
  float a0 = 0.5f * (llv0 + lh0 + hl0 + hh0) + bv;
  float b0 = 0.5f * (llv0 + lh0 - hl0 - hh0) + bv;
  float c0 = 0.5f * (llv0 - lh0 + hl0 - hh0) + bv;
  float d0 = 0.5f * (llv0 - lh0 - hl0 + hh0) + bv;
  float a1 = 0.5f * (llv1 + lh1 + hl1 + hh1) + bv;
  float b1 = 0.5f * (llv1 + lh1 - hl1 - hh1) + bv;
  float c1 = 0.5f * (llv1 - lh1 + hl1 - hh1) + bv;
  float d1 = 0.5f * (llv1 - lh1 - hl1 + hh1) + bv;
  long obase = (((long)(b * 64 + c) * (2 * H2) + 2 * h2) * (2 * W2)) + 2 * w2;
  *(float4*)(out + obase)          = make_float4(a0, b0, a1, b1);
  *(float4*)(out + obase + 2 * W2) = make_float4(c0, d0, c1, d1);
}

// ---------------- workspace layout (bytes) ----------------
constexpr size_t WBF_SZ1 = 25ull * 256 * 256 * 2;
constexpr size_t OFF_WBF = 0;
constexpr size_t OFF_S0  = 3 * WBF_SZ1;
constexpr size_t S0_SZ   = 8ull * 132 * 132 * 256 * 2;
constexpr size_t REL_S1 = 0;
constexpr size_t S1_SZ  = 8ull * 68 * 68 * 256 * 2;
constexpr size_t REL_L1 = REL_S1 + S1_SZ;
constexpr size_t L1_SZ  = 8ull * 64 * 64 * 64 * 4;
constexpr size_t REL_S2 = REL_L1 + L1_SZ;
constexpr size_t S2_SZ  = 8ull * 36 * 36 * 256 * 2;
constexpr size_t REL_Y1 = REL_S2 + S2_SZ;
constexpr size_t Y1_SZ  = 8ull * 64 * 64 * 256 * 2;
constexpr size_t REL_Y2 = REL_Y1 + Y1_SZ;
constexpr size_t Y2_SZ  = 8ull * 32 * 32 * 256 * 2;
constexpr size_t REL_N2 = REL_Y2 + Y2_SZ;
constexpr size_t N2_SZ  = 8ull * 64 * 64 * 64 * 4;
constexpr size_t REL_L2 = REL_N2 + N2_SZ;
constexpr size_t OFF_L0 = OFF_S0 + S0_SZ;
constexpr size_t L0_SZ  = 8ull * 64 * 128 * 128 * 4;
constexpr size_t OFF_Y0 = OFF_L0 + L0_SZ;
constexpr size_t Y0_SZ  = 8ull * 128 * 128 * 256 * 2;

extern "C" void kernel_launch(void* const* d_in, const int* in_sizes, int n_in,
                              void* d_out, int out_size, void* d_ws, size_t ws_size,
                              hipStream_t stream) {
  const float* x    = (const float*)d_in[0];
  const float* w0   = (const float*)d_in[1];
  const float* w1   = (const float*)d_in[2];
  const float* w2   = (const float*)d_in[3];
  const float* bias = (const float*)d_in[4];
  float* out = (float*)d_out;
  char* ws = (char*)d_ws;

  u16* wbf0 = (u16*)(ws + OFF_WBF);
  u16* wbf1 = (u16*)(ws + OFF_WBF + WBF_SZ1);
  u16* wbf2 = (u16*)(ws + OFF_WBF + 2 * WBF_SZ1);
  u16* s0 = (u16*)(ws + OFF_S0);
  u16* s1 = (u16*)(ws + OFF_S0 + REL_S1);
  float* l1 = (float*)(ws + OFF_S0 + REL_L1);
  u16* s2 = (u16*)(ws + OFF_S0 + REL_S2);
  u16* y1 = (u16*)(ws + OFF_S0 + REL_Y1);
  u16* y2 = (u16*)(ws + OFF_S0 + REL_Y2);
  float* n2 = (float*)(ws + OFF_S0 + REL_N2);
  float* l2 = (float*)(ws + OFF_S0 + REL_L2);
  float* l0 = (float*)(ws + OFF_L0);
  float* n1 = (float*)(ws + OFF_L0);   // aliases l0 (dead after dwt1)
  u16* y0 = (u16*)(ws + OFF_Y0);

  k_wtrans<<<256, 256, 0, stream>>>(w0, wbf0);
  k_wtrans<<<256, 256, 0, stream>>>(w1, wbf1);
  k_wtrans<<<256, 256, 0, stream>>>(w2, wbf2);

  // level 0
  k_border<<<2080, 256, 0, stream>>>(s0, 8, 128, 128);
  k_dwt<<<16384, 256, 0, stream>>>(x, s0, l0, 8, 128, 128);
  k_conv8<<<512, 512, 0, stream>>>(s0, wbf0, y0, 128, 128);

  k_border<<<1056, 256, 0, stream>>>(s1, 8, 64, 64);
  k_border<<<544, 256, 0, stream>>>(s2, 8, 32, 32);

  // level 1
  k_dwt<<<4096, 256, 0, stream>>>(l0, s1, l1, 8, 64, 64);
  k_conv_p<<<256, 512, 0, stream>>>(s1, wbf1, y1, 64, 64);

  // level 2
  k_dwt<<<1024, 256, 0, stream>>>(l1, s2, l2, 8, 32, 32);
  k_conv<<<dim3(64, 2), 256, 0, stream>>>(s2, wbf2, y2, 32, 32);

  // reconstruction
  k_idwt<<<1024, 256, 0, stream>>>(y2, nullptr, n2, nullptr, 8, 32, 32);
  k_idwt<<<4096, 256, 0, stream>>>(y1, n2, n1, nullptr, 8, 64, 64);
  k_idwt<<<16384, 256, 0, stream>>>(y0, n1, out, bias, 8, 128, 128);
}

// Round 5
// 632.675 us; speedup vs baseline: 1.4561x; 1.1306x over previous
//
#include <hip/hip_runtime.h>

// WTConv2d: 3-level Haar DWT -> 5x5 conv (256ch) per level -> IDWT pyramid + bias.
// Unified conv kernel: 256-row x 256-col implicit GEMM, 4 quadrant-phases/K-tile,
// full-lead ds_read pipelining (separate b0/b1 reg sets), counted lgkm gates,
// one free vmcnt(0)/tile, K-split support (bf16 partials + reduce).

typedef unsigned short u16;
typedef __attribute__((ext_vector_type(8))) __bf16 bf16x8;
typedef __attribute__((ext_vector_type(4))) float f32x4;

__device__ __forceinline__ u16 f2bf(float f) {
  union { float f; unsigned u; } v; v.f = f;
  unsigned r = v.u + 0x7fffu + ((v.u >> 16) & 1u);   // RNE
  return (u16)(r >> 16);
}
__device__ __forceinline__ float bf2f(u16 u) {
  union { unsigned u; float f; } v; v.u = ((unsigned)u) << 16;
  return v.f;
}

typedef const unsigned int __attribute__((address_space(1)))* gas1_t;
typedef unsigned int __attribute__((address_space(3)))* gas3_t;
__device__ __forceinline__ void gload16(const void* g, void* l) {
  __builtin_amdgcn_global_load_lds((gas1_t)g, (gas3_t)l, 16, 0, 0);
}

// ---------------- weight transform: OIHW fp32 -> [tap][co][ci] bf16 ----------------
__global__ void k_wtrans(const float* __restrict__ w, u16* __restrict__ wb) {
  int co = blockIdx.x;
  int ci = threadIdx.x;
  const float* src = w + ((long)co * 256 + ci) * 25;
  float v[25];
#pragma unroll
  for (int tp = 0; tp < 25; ++tp) v[tp] = src[tp];
#pragma unroll
  for (int tp = 0; tp < 25; ++tp)
    wb[((long)tp * 256 + co) * 256 + ci] = f2bf(v[tp]);
}

// ---------------- border zero (pad frame of stacked buffer) ----------------
__global__ void k_border(u16* __restrict__ st, int B_, int H2, int W2) {
  int PW = W2 + 4;
  int npix = 4 * PW + 4 * H2;
  int gid = blockIdx.x * blockDim.x + threadIdx.x;
  int pid = gid >> 6, lane = gid & 63;
  if (pid >= B_ * npix) return;
  int b = pid / npix, p = pid % npix;
  int row, col;
  if (p < 2 * PW) { row = p / PW; col = p % PW; }
  else if (p < 4 * PW) { int q = p - 2 * PW; row = H2 + 2 + q / PW; col = q % PW; }
  else { int q = p - 4 * PW; row = 2 + (q >> 2); int c4 = q & 3; col = (c4 < 2) ? c4 : W2 + c4; }
  long base = (((long)b * (H2 + 4) + row) * PW + col) * 256 + lane * 4;
  *(ushort4*)(st + base) = make_ushort4(0, 0, 0, 0);
}

// ---------------- DWT: fp32 NCHW -> stacked bf16 padded NHWC + ll fp32 ----------------
__global__ void k_dwt(const float* __restrict__ in, u16* __restrict__ st,
                      float* __restrict__ ll, int B_, int H2, int W2) {
  int idx = blockIdx.x * blockDim.x + threadIdx.x;
  int W2h = W2 >> 1;
  int total = B_ * 64 * H2 * W2h;
  if (idx >= total) return;
  int w2h = idx % W2h; int t2 = idx / W2h;
  int h2 = t2 % H2; t2 /= H2;
  int c = t2 % 64; int b = t2 / 64;
  int w2 = w2h * 2;
  const float* r0 = in + (((long)(b * 64 + c) * (2 * H2) + 2 * h2) * (2 * W2)) + 2 * w2;
  const float* r1 = r0 + 2 * W2;
  float4 tp = *(const float4*)r0;
  float4 bt = *(const float4*)r1;
  float ll0 = 0.5f * (tp.x + tp.y + bt.x + bt.y);
  float lh0 = 0.5f * (tp.x + tp.y - bt.x - bt.y);
  float hl0 = 0.5f * (tp.x - tp.y + bt.x - bt.y);
  float hh0 = 0.5f * (tp.x - tp.y - bt.x + bt.y);
  float ll1 = 0.5f * (tp.z + tp.w + bt.z + bt.w);
  float lh1 = 0.5f * (tp.z + tp.w - bt.z - bt.w);
  float hl1 = 0.5f * (tp.z - tp.w + bt.z - bt.w);
  float hh1 = 0.5f * (tp.z - tp.w - bt.z + bt.w);
  long sbase = (((long)b * (H2 + 4) + (h2 + 2)) * (W2 + 4) + (w2 + 2)) * 256 + 4 * c;
  *(ushort4*)(st + sbase)       = make_ushort4(f2bf(ll0), f2bf(lh0), f2bf(hl0), f2bf(hh0));
  *(ushort4*)(st + sbase + 256) = make_ushort4(f2bf(ll1), f2bf(lh1), f2bf(hl1), f2bf(hh1));
  long lbase = (((long)(b * 64 + c) * H2) + h2) * W2 + w2;
  *(float2*)(ll + lbase) = make_float2(ll0, ll1);
}

// ---------------- 256x256 conv, full-lead cross-phase pipelining ----------------
// Phases (0,0)(1,0)(1,1)(0,1). Reads: P0 a1,b1(cur); ph3-post b0'(alt); ph4-post a0'(alt).
// Gates: B1 lgkm(12), B2 lgkm(4), B3 lgkm(0), B4 none. Stage: ph3 A(kt+2), ph4 B(kt+2).
// vmcnt(0) pre-B3 (drains only >=4-phase-old loads). K-split via (ktot, nsplit).
__global__ __launch_bounds__(512, 2) void k_conv8(
    const u16* __restrict__ st, const u16* __restrict__ wt, u16* __restrict__ out,
    int H2, int W2, int ktot, int nsplit) {
  __shared__ __align__(16) char smem[131072];   // 2 bufs x (A 32K + B 32K)
  const int t = threadIdx.x;
  const int lane = t & 63;
  const int wv = t >> 6;
  const int wm = wv >> 2, wn = wv & 3;          // 2M x 4N waves; wave tile 128x64
  const int nwg = gridDim.x;
  const int bid = blockIdx.x;
  const int lb = (bid & 7) * (nwg >> 3) + (bid >> 3);  // XCD-chunked (nwg%8==0)
  const int m0 = lb * 256;
  const int PW = W2 + 4;
  const int spl = blockIdx.y;
  const int kk0 = (spl * ktot) / nsplit;
  const int kk1 = ((spl + 1) * ktot) / nsplit;
  const long Mrows = (long)nwg * 256;
  u16* yo = out + (long)spl * Mrows * 256;

  // staging sources (source-side XOR swizzle)
  const int trow = t >> 3;
  const int srcci = ((t & 7) ^ (trow & 7)) * 8;
  const char* baseA[4];
#pragma unroll
  for (int u = 0; u < 4; ++u) {
    int m = m0 + u * 64 + trow;
    int w = m % W2; int q = m / W2;
    int hh = q % H2; int b = q / H2;
    long sp = ((long)(b * (H2 + 4) + hh + 2) * PW + (w + 2));
    baseA[u] = (const char*)(st + sp * 256 + srcci);
  }
  const char* baseB0 = (const char*)(wt + trow * 256 + srcci);

  f32x4 acc[8][4];
#pragma unroll
  for (int i = 0; i < 8; ++i)
#pragma unroll
    for (int j = 0; j < 4; ++j) acc[i][j] = f32x4{0.f, 0.f, 0.f, 0.f};

  // per-lane LDS read addresses for buffer 0; bit 16 toggles buffer
  const int kq = (lane >> 4) * 16;
  const int sw = (lane & 7) << 4;
  int va0 = (wm * 128 + (lane & 15)) * 128 + (kq ^ sw);
  int va1 = (wm * 128 + (lane & 15)) * 128 + ((64 + kq) ^ sw);
  int vb0 = 32768 + (wn * 64 + (lane & 15)) * 128 + (kq ^ sw);
  int vb1 = 32768 + (wn * 64 + (lane & 15)) * 128 + ((64 + kq) ^ sw);

  bf16x8 a0[4][2], a1[4][2], b0[2][2], b1[2][2];

  auto offsets = [&](int kk, long& oA, long& oB) {
    int tap = kk >> 2, cic = kk & 3;
    int dy = tap / 5 - 2, dx = tap % 5 - 2;
    oA = ((long)(dy * PW + dx) * 256 + cic * 64) * 2;
    oB = ((long)tap * 65536 + cic * 64) * 2;
  };
  auto stageA4 = [&](long off, int dsto) {
    char* d = smem + dsto + wv * 1024;
#pragma unroll
    for (int u = 0; u < 4; ++u) gload16(baseA[u] + off, d + u * 8192);
  };
  auto stageB4 = [&](long off, int dsto) {
    char* d = smem + dsto + 32768 + wv * 1024;
#pragma unroll
    for (int u = 0; u < 4; ++u) gload16(baseB0 + u * 32768 + off, d + u * 8192);
  };

#define LDA0 { _Pragma("unroll") for (int i = 0; i < 4; ++i) {       \
    a0[i][0] = *(const bf16x8*)(smem + va0 + i * 2048);              \
    a0[i][1] = *(const bf16x8*)(smem + va1 + i * 2048); } }
#define LDA1 { _Pragma("unroll") for (int i = 0; i < 4; ++i) {       \
    a1[i][0] = *(const bf16x8*)(smem + va0 + 8192 + i * 2048);       \
    a1[i][1] = *(const bf16x8*)(smem + va1 + 8192 + i * 2048); } }
#define LDB0 { _Pragma("unroll") for (int j = 0; j < 2; ++j) {       \
    b0[j][0] = *(const bf16x8*)(smem + vb0 + j * 2048);              \
    b0[j][1] = *(const bf16x8*)(smem + vb1 + j * 2048); } }
#define LDB1 { _Pragma("unroll") for (int j = 0; j < 2; ++j) {       \
    b1[j][0] = *(const bf16x8*)(smem + vb0 + 4096 + j * 2048);       \
    b1[j][1] = *(const bf16x8*)(smem + vb1 + 4096 + j * 2048); } }
#define MMQ(A, B, IB, JB)                                                     \
  _Pragma("unroll") for (int i = 0; i < 4; ++i)                               \
  _Pragma("unroll") for (int j = 0; j < 2; ++j)                               \
  _Pragma("unroll") for (int k = 0; k < 2; ++k)                               \
    acc[(IB) + i][(JB) + j] = __builtin_amdgcn_mfma_f32_16x16x32_bf16(        \
        A[i][k], B[j][k], acc[(IB) + i][(JB) + j], 0, 0, 0);

  // prologue: tile kk0 -> buf0, kk0+1 -> buf1; read a0,b0 of kk0
  long oA, oB;
  offsets(kk0, oA, oB);
  stageA4(oA, 0); stageB4(oB, 0);
  offsets(kk0 + 1, oA, oB);
  stageA4(oA, 65536); stageB4(oB, 65536);
  asm volatile("s_waitcnt vmcnt(8)" ::: "memory");
  __builtin_amdgcn_s_barrier();
  LDA0 LDB0

  int curo = 0;
  for (int kt = kk0; kt < kk1; ++kt) {
    const bool stg = (kt + 2) < kk1;
    const bool rd1 = (kt + 1) < kk1;
    // P0: remaining cur reads; then flip address regs to alt
    LDA1 LDB1
    va0 ^= 65536; va1 ^= 65536; vb0 ^= 65536; vb1 ^= 65536;
    // ph1 (0,0)
    __builtin_amdgcn_s_barrier();
    asm volatile("s_waitcnt lgkmcnt(12)" ::: "memory");
    __builtin_amdgcn_sched_barrier(0);
    __builtin_amdgcn_s_setprio(1);
    MMQ(a0, b0, 0, 0)
    __builtin_amdgcn_s_setprio(0);
    // ph2 (1,0)
    __builtin_amdgcn_s_barrier();
    asm volatile("s_waitcnt lgkmcnt(4)" ::: "memory");
    __builtin_amdgcn_sched_barrier(0);
    __builtin_amdgcn_s_setprio(1);
    MMQ(a1, b0, 4, 0)
    __builtin_amdgcn_s_setprio(0);
    if (rd1) { asm volatile("s_waitcnt vmcnt(0)" ::: "memory"); }  // drains only old loads
    // ph3 (1,1)
    __builtin_amdgcn_s_barrier();
    asm volatile("s_waitcnt lgkmcnt(0)" ::: "memory");
    __builtin_amdgcn_sched_barrier(0);
    __builtin_amdgcn_s_setprio(1);
    MMQ(a1, b1, 4, 2)
    __builtin_amdgcn_s_setprio(0);
    if (rd1) { LDB0 }                                   // b0'(kt+1) from alt
    if (stg) { offsets(kt + 2, oA, oB); stageA4(oA, curo); }
    // ph4 (0,1)
    __builtin_amdgcn_s_barrier();
    __builtin_amdgcn_s_setprio(1);
    MMQ(a0, b1, 0, 2)
    __builtin_amdgcn_s_setprio(0);
    if (stg) { stageB4(oB, curo); }
    if (rd1) { LDA0 }                                   // a0'(kt+1) from alt
    curo ^= 65536;
  }
#undef MMQ
#undef LDA0
#undef LDA1
#undef LDB0
#undef LDB1

  // epilogue: C/D layout col=lane&15 (n), row=(lane>>4)*4+reg (m)
#pragma unroll
  for (int i = 0; i < 8; ++i) {
    int mloc = m0 + wm * 128 + i * 16 + (lane >> 4) * 4;
#pragma unroll
    for (int j = 0; j < 4; ++j) {
      int nloc = wn * 64 + j * 16 + (lane & 15);
#pragma unroll
      for (int r = 0; r < 4; ++r)
        yo[(long)(mloc + r) * 256 + nloc] = f2bf(acc[i][j][r]);
    }
  }
}

// ---------------- reduce K-split bf16 partials -> bf16 ----------------
__global__ void k_red(const u16* __restrict__ p, u16* __restrict__ y, long n, int ns) {
  long i = ((long)blockIdx.x * 256 + threadIdx.x) * 4;
  if (i >= n) return;
  float s0 = 0.f, s1 = 0.f, s2 = 0.f, s3 = 0.f;
  for (int k = 0; k < ns; ++k) {
    ushort4 v = *(const ushort4*)(p + (long)k * n + i);
    s0 += bf2f(v.x); s1 += bf2f(v.y); s2 += bf2f(v.z); s3 += bf2f(v.w);
  }
  *(ushort4*)(y + i) = make_ushort4(f2bf(s0), f2bf(s1), f2bf(s2), f2bf(s3));
}

// ---------------- IDWT ----------------
__global__ void k_idwt(const u16* __restrict__ y, const float* __restrict__ nll,
                       float* __restrict__ out, const float* __restrict__ bias,
                       int B_, int H2, int W2) {
  int idx = blockIdx.x * blockDim.x + threadIdx.x;
  int W2h = W2 >> 1;
  int total = B_ * 64 * H2 * W2h;
  if (idx >= total) return;
  int w2h = idx % W2h; int t2 = idx / W2h;
  int h2 = t2 % H2; t2 /= H2;
  int c = t2 % 64; int b = t2 / 64;
  int w2 = w2h * 2;
  long ybase = (((long)b * H2 + h2) * W2 + w2) * 256 + 4 * c;
  ushort4 q0 = *(const ushort4*)(y + ybase);
  ushort4 q1 = *(const ushort4*)(y + ybase + 256);
  float llv0 = bf2f(q0.x), lh0 = bf2f(q0.y), hl0 = bf2f(q0.z), hh0 = bf2f(q0.w);
  float llv1 = bf2f(q1.x), lh1 = bf2f(q1.y), hl1 = bf2f(q1.z), hh1 = bf2f(q1.w);
  if (nll) {
    float2 nv = *(const float2*)(nll + (((long)(b * 64 + c) * H2 + h2) * W2 + w2));
    llv0 += nv.x; llv1 += nv.y;
  }
  float bv = bias ? bias[c] : 0.f;
  float a0 = 0.5f * (llv0 + lh0 + hl0 + hh0) + bv;
  float b0 = 0.5f * (llv0 + lh0 - hl0 - hh0) + bv;
  float c0 = 0.5f * (llv0 - lh0 + hl0 - hh0) + bv;
  float d0 = 0.5f * (llv0 - lh0 - hl0 + hh0) + bv;
  float a1 = 0.5f * (llv1 + lh1 + hl1 + hh1) + bv;
  float b1 = 0.5f * (llv1 + lh1 - hl1 - hh1) + bv;
  float c1 = 0.5f * (llv1 - lh1 + hl1 - hh1) + bv;
  float d1 = 0.5f * (llv1 - lh1 - hl1 + hh1) + bv;
  long obase = (((long)(b * 64 + c) * (2 * H2) + 2 * h2) * (2 * W2)) + 2 * w2;
  *(float4*)(out + obase)          = make_float4(a0, b0, a1, b1);
  *(float4*)(out + obase + 2 * W2) = make_float4(c0, d0, c1, d1);
}

// ---------------- workspace layout (bytes) ----------------
constexpr size_t WBF_SZ1 = 25ull * 256 * 256 * 2;
constexpr size_t OFF_WBF = 0;
constexpr size_t OFF_S0  = 3 * WBF_SZ1;
constexpr size_t S0_SZ   = 8ull * 132 * 132 * 256 * 2;
constexpr size_t REL_S1 = 0;
constexpr size_t S1_SZ  = 8ull * 68 * 68 * 256 * 2;
constexpr size_t REL_L1 = REL_S1 + S1_SZ;
constexpr size_t L1_SZ  = 8ull * 64 * 64 * 64 * 4;
constexpr size_t REL_S2 = REL_L1 + L1_SZ;
constexpr size_t S2_SZ  = 8ull * 36 * 36 * 256 * 2;
constexpr size_t REL_Y1 = REL_S2 + S2_SZ;
constexpr size_t Y1_SZ  = 8ull * 64 * 64 * 256 * 2;
constexpr size_t REL_Y2 = REL_Y1 + Y1_SZ;
constexpr size_t Y2_SZ  = 8ull * 32 * 32 * 256 * 2;
constexpr size_t REL_N2 = REL_Y2 + Y2_SZ;
constexpr size_t N2_SZ  = 8ull * 64 * 64 * 64 * 4;
constexpr size_t REL_L2 = REL_N2 + N2_SZ;
constexpr size_t OFF_L0 = OFF_S0 + S0_SZ;    // 33.5MB region: l0, then partials P, then n1
constexpr size_t OFF_Y0 = OFF_L0 + 8ull * 64 * 128 * 128 * 4;

extern "C" void kernel_launch(void* const* d_in, const int* in_sizes, int n_in,
                              void* d_out, int out_size, void* d_ws, size_t ws_size,
                              hipStream_t stream) {
  const float* x    = (const float*)d_in[0];
  const float* w0   = (const float*)d_in[1];
  const float* w1   = (const float*)d_in[2];
  const float* w2   = (const float*)d_in[3];
  const float* bias = (const float*)d_in[4];
  float* out = (float*)d_out;
  char* ws = (char*)d_ws;

  u16* wbf0 = (u16*)(ws + OFF_WBF);
  u16* wbf1 = (u16*)(ws + OFF_WBF + WBF_SZ1);
  u16* wbf2 = (u16*)(ws + OFF_WBF + 2 * WBF_SZ1);
  u16* s0 = (u16*)(ws + OFF_S0);
  u16* s1 = (u16*)(ws + OFF_S0 + REL_S1);
  float* l1 = (float*)(ws + OFF_S0 + REL_L1);
  u16* s2 = (u16*)(ws + OFF_S0 + REL_S2);
  u16* y1 = (u16*)(ws + OFF_S0 + REL_Y1);
  u16* y2 = (u16*)(ws + OFF_S0 + REL_Y2);
  float* n2 = (float*)(ws + OFF_S0 + REL_N2);
  float* l2 = (float*)(ws + OFF_S0 + REL_L2);
  float* l0 = (float*)(ws + OFF_L0);
  u16* P   = (u16*)(ws + OFF_L0);      // partials; aliases l0 (dead after dwt1)
  float* n1 = (float*)(ws + OFF_L0);   // aliases P (dead after k_red2)
  u16* y0 = (u16*)(ws + OFF_Y0);

  k_wtrans<<<256, 256, 0, stream>>>(w0, wbf0);
  k_wtrans<<<256, 256, 0, stream>>>(w1, wbf1);
  k_wtrans<<<256, 256, 0, stream>>>(w2, wbf2);

  // level 0
  k_border<<<2080, 256, 0, stream>>>(s0, 8, 128, 128);
  k_dwt<<<16384, 256, 0, stream>>>(x, s0, l0, 8, 128, 128);
  k_conv8<<<dim3(512, 1), 512, 0, stream>>>(s0, wbf0, y0, 128, 128, 100, 1);

  k_border<<<1056, 256, 0, stream>>>(s1, 8, 64, 64);
  k_border<<<544, 256, 0, stream>>>(s2, 8, 32, 32);

  // level 1 (K-split 2, bf16 partials -> reduce)
  k_dwt<<<4096, 256, 0, stream>>>(l0, s1, l1, 8, 64, 64);
  k_conv8<<<dim3(128, 2), 512, 0, stream>>>(s1, wbf1, P, 64, 64, 100, 2);
  k_red<<<8192, 256, 0, stream>>>(P, y1, 8388608L, 2);

  // level 2 (K-split 8)
  k_dwt<<<1024, 256, 0, stream>>>(l1, s2, l2, 8, 32, 32);
  k_conv8<<<dim3(32, 8), 512, 0, stream>>>(s2, wbf2, P, 32, 32, 100, 8);
  k_red<<<2048, 256, 0, stream>>>(P, y2, 2097152L, 8);

  // reconstruction
  k_idwt<<<1024, 256, 0, stream>>>(y2, nullptr, n2, nullptr, 8, 32, 32);
  k_idwt<<<4096, 256, 0, stream>>>(y1, n2, n1, nullptr, 8, 64, 64);
  k_idwt<<<16384, 256, 0, stream>>>(y0, n1, out, bias, 8, 128, 128);
}